// Round 4
// baseline (557.397 us; speedup 1.0000x reference)
//
#include <hip/hip_runtime.h>
#include <math.h>

#define T_DIM 1000
#define C_DIM 500
#define U_DIM 100
#define PAD   16          // head/tail padding rows for P
#define AROWS (T_DIM + 5) // A/Braw rows (loss pipeline reads to row T+4)
#define NEGINF (-INFINITY)
#define LROW  128         // LDS row stride in floats; cols 100..127 = -inf pad
#define CANU  0x7fbadbadu // canary NaN: scan values are never NaN (fmaxf fix)
#define CANF  __uint_as_float(CANU)

// ---- scalar lse helpers: bit-identical to reference op order (validated
// rounds r1-r3, absmax 0.0).  All-dead case -> NaN -> fmaxf(r,-inf) = -inf.
__device__ __forceinline__ float lse2s(float a, float b) {
    float m = fmaxf(a, b), mn = fminf(a, b);
    float r = m + __logf(1.0f + __expf(mn - m));
    return fmaxf(r, NEGINF);
}
__device__ __forceinline__ float lse3s(float x1, float x2, float x3) {
    float m = fmaxf(fmaxf(x1, x2), x3);
    float r = m + __logf(__expf(x1 - m) + __expf(x2 - m) + __expf(x3 - m));
    return fmaxf(r, NEGINF);
}
// scalar lse3 for the fallback kernels (original guard form)
__device__ __forceinline__ float lse3f(float x1, float x2, float x3) {
    float m = fmaxf(fmaxf(x1, x2), x3);
    if (m == NEGINF) return NEGINF;
    return m + __logf(__expf(x1 - m) + __expf(x2 - m) + __expf(x3 - m));
}

// Bug-compatible replica of reference _log_sub_exp (incl. inf-substitution quirk).
__device__ __forceinline__ float log_sub_expf(float a, float b) {
    bool ia = isinf(a), ib = isinf(b);
    if (!ia && !ib) {
        float ans = b + __logf(__expf(a - b) - 1.0f);
        if (isinf(ans)) ans = -2001.0f + __logf(__expf(1.0f) - 1.0f);
        return ans;
    }
    if (!ia && ib) return a;
    return NEGINF;
}

// DPP lane shifts (validated bit-exact rounds 6-10)
__device__ __forceinline__ float dpp_shr1(float x) {  // lane L <- L-1; lane0 <- -inf
    int r = __builtin_amdgcn_update_dpp(__float_as_int(NEGINF), __float_as_int(x),
                                        0x138, 0xF, 0xF, false);  // wave_shr:1
    return __int_as_float(r);
}
__device__ __forceinline__ float dpp_shl1(float x) {  // lane L <- L+1; lane63 <- -inf
    int r = __builtin_amdgcn_update_dpp(__float_as_int(NEGINF), __float_as_int(x),
                                        0x130, 0xF, 0xF, false);  // wave_shl:1
    return __int_as_float(r);
}

// ---- loss step (verbatim r10) ----------------------------------------------
#define LSTEP(tt, RA, RB, RP)                                                \
    {                                                                        \
        float a_nx = (RA), br_nx = (RB), p_nx = (RP);                        \
        float bl   = (a_t  == NEGINF) ? NEGINF : braw_t;                     \
        float term = (a_nx == NEGINF) ? NEGINF : (br_nx + p_nx);             \
        float bp = log_sub_expf(bl, term);                                   \
        float x = a_t + bp - 0.1f * (float)(tt) * inv_hl;                    \
        if (x != NEGINF) {                                                   \
            float nm = fmaxf(m, x);                                          \
            ssum = ssum * __expf(m - nm) + __expf(x - nm);                   \
            m = nm;                                                          \
        }                                                                    \
        a_t = a_nx; braw_t = br_nx;                                          \
    }

// ---- loader gather: 50 rows x (100 labels + blank) straight from nnet ------
// LDS copy is pre-masked: labels with u >= yl -> NEGINF; global P keeps raw.
__device__ __forceinline__ void gather_chunk(
    const float* __restrict__ nb, const int* __restrict__ shY, int yl,
    float* __restrict__ lds, float* __restrict__ ldsb,
    float* __restrict__ Pg /* global row0 base, or nullptr */,
    int row0, int j)
{
#pragma unroll
    for (int k = 0; k < 17; ++k) {
        int i = j + k * 384;                 // 384 loader threads per direction
        if (i < 6400) {                      // 50 rows x 128 slots
            int r = i >> 7, q = i & 127;
            if (q <= 100) {
                int row = row0 + r;
                int col = (q < 100) ? shY[q] : 0;
                float v = (row < T_DIM) ? nb[(size_t)row * C_DIM + col] : NEGINF;
                if (q < 100) {
                    lds[r * LROW + q] = (q < yl) ? v : NEGINF;
                    if (Pg) Pg[(size_t)r * U_DIM + q] = v;
                } else {
                    ldsb[r] = v;
                }
            }
        }
    }
}

// ======================= scan step macros (2 states/lane) ===================
// FWD producer (states 0..100; lane L: E=s2L, O=s2L+1; lane50 O dead):
#define FWP(j, pOv, gv)                                                      \
    {                                                                        \
        const int t_ = tbk + (j);                                            \
        float Osh = dpp_shr1(O0);                                            \
        float nE = (mzE_lo + (gv)) + lse2s(E0, Osh);                         \
        float nO = (pOv) + lse3s(O0, E0, Osh + mskFlo);                      \
        float nOsh = dpp_shr1(nO);                                           \
        volatile float* rp = (L == 50)                                       \
            ? (volatile float*)(rlyF + 2 * (t_ & 31)) : dmp;                 \
        rp[0] = nOsh; rp[1] = nE;  /* lane50: (a[99], a[100]) */             \
        E0 = nE; O0 = nO;                                                    \
        if (st) stA[(j) * U_DIM] = nO;                                       \
    }

// FWD consumer (states 101..200; lane L: O=s101+2L, E=s102+2L):
#define FWC(j, pOv, gv)                                                      \
    {                                                                        \
        const int t_ = tbk + (j);                                            \
        const int sl_ = (t_ + 31) & 31;                                      \
        float r0 = *(volatile const float*)(rlyF + 2 * sl_);                 \
        float r1 = *(volatile const float*)(rlyF + 2 * sl_ + 1);             \
        while (__float_as_uint(r0) == CANU || __float_as_uint(r1) == CANU) { \
            __builtin_amdgcn_s_sleep(1);                                     \
            r0 = *(volatile const float*)(rlyF + 2 * sl_);                   \
            r1 = *(volatile const float*)(rlyF + 2 * sl_ + 1);               \
        }                                                                    \
        asm volatile("" ::: "memory");                                       \
        float Esh = dpp_shr1(E0); Esh = (L == 0) ? r1 : Esh;                 \
        float Osh = dpp_shr1(O0); Osh = (L == 0) ? r0 : Osh;                 \
        float nE = (mzE_hi + (gv)) + lse2s(E0, O0);                          \
        float nO = (pOv) + lse3s(O0, Esh, Osh + mskFhi);                     \
        volatile float* cp = (L == 0)                                        \
            ? (volatile float*)(rlyF + 2 * sl_) : dmp;                       \
        cp[0] = CANF; cp[1] = CANF;                                          \
        E0 = nE; O0 = nO;                                                    \
        if (st) stA[(j) * U_DIM] = nO;                                       \
        if (((t_) & 7) == 7) {                                               \
            asm volatile("s_waitcnt lgkmcnt(0)" ::: "memory");               \
            volatile int* pp = (L == 0) ? (volatile int*)&prgFC              \
                                        : (volatile int*)dmp;                \
            *pp = t_ + 1;                                                    \
        }                                                                    \
    }

// BWD producer (states 101..200): relay q[101] (lane0 qO) early each step.
#define BWP(j, pOv, gv, FINF)                                                \
    {                                                                        \
        const int t_ = tbk - (j);                                            \
        const int k_ = 999 - t_;                                             \
        float qE = (mzE_hi + (gv)) + BE;                                     \
        float qO = (pOv) + BO;                                               \
        volatile float* rp = (L == 0)                                        \
            ? (volatile float*)(rlyB + (k_ & 31)) : dmp;                     \
        rp[0] = qO;                                                          \
        float qOsh = dpp_shl1(qO);                                           \
        float nE = lse2s(qE, qOsh);                                          \
        float nO = lse3s(qO, qE, qOsh + mskBhi);                             \
        if (FINF) { const bool fin = (t_ == hl1);                            \
            BE = fin ? fE_hi : nE; BO = fin ? fO_hi : nO;                    \
        } else { BE = nE; BO = nO; }                                         \
        if (st) stB[-(int)((j) * U_DIM)] = BO;                               \
    }

// BWD consumer (states 0..100): inject relayed q[101] at lane50's qO.
#define BWC(j, pOv, gv, FINF)                                                \
    {                                                                        \
        const int t_ = tbk - (j);                                            \
        const int k_ = 999 - t_;                                             \
        const int sl_ = k_ & 31;                                             \
        float r0 = *(volatile const float*)(rlyB + sl_);                     \
        while (__float_as_uint(r0) == CANU) {                                \
            __builtin_amdgcn_s_sleep(1);                                     \
            r0 = *(volatile const float*)(rlyB + sl_);                       \
        }                                                                    \
        asm volatile("" ::: "memory");                                       \
        float qE = (mzE_lo + (gv)) + BE;                                     \
        float qO = (pOv) + BO;                                               \
        qO = (L == 50) ? r0 : qO;                                            \
        float qEsh = dpp_shl1(qE);                                           \
        float qOsh = dpp_shl1(qO);                                           \
        float nE = lse2s(qE, qO);                                            \
        float nO = lse3s(qO, qEsh, qOsh + mskBlo);                           \
        volatile float* cp = (L == 0)                                        \
            ? (volatile float*)(rlyB + sl_) : dmp;                           \
        cp[0] = CANF;                                                        \
        if (FINF) { const bool fin = (t_ == hl1);                            \
            BE = fin ? fE_lo : nE; BO = fin ? fO_lo : nO;                    \
        } else { BE = nE; BO = nO; }                                         \
        if (st) stB[-(int)((j) * U_DIM)] = BO;                               \
        if ((k_ & 7) == 7) {                                                 \
            asm volatile("s_waitcnt lgkmcnt(0)" ::: "memory");               \
            volatile int* pp = (L == 0) ? (volatile int*)&prgBC              \
                                        : (volatile int*)dmp;                \
            *pp = k_ + 1;                                                    \
        }                                                                    \
    }

#define BWP_BLOCK(FINF)                                                      \
    {                                                                        \
        const int kst = 999 - (tb2 + kk);                                    \
        if (kst >= 30) {                                                     \
            const int need = kst - 21;                                       \
            while (*(volatile int*)&prgBC < need)                            \
                __builtin_amdgcn_s_sleep(8);                                 \
            asm volatile("" ::: "memory");                                   \
        }                                                                    \
        const int tbk = tb2 + kk;                                            \
        float p0 = bb2[(kk-0)*LROW + 50 + L], p1 = bb2[(kk-1)*LROW + 50 + L],\
              p2 = bb2[(kk-2)*LROW + 50 + L], p3 = bb2[(kk-3)*LROW + 50 + L],\
              p4 = bb2[(kk-4)*LROW + 50 + L], p5 = bb2[(kk-5)*LROW + 50 + L],\
              p6 = bb2[(kk-6)*LROW + 50 + L], p7 = bb2[(kk-7)*LROW + 50 + L],\
              p8 = bb2[(kk-8)*LROW + 50 + L], p9 = bb2[(kk-9)*LROW + 50 + L];\
        float g0 = bp2[kk-0], g1 = bp2[kk-1], g2 = bp2[kk-2], g3 = bp2[kk-3],\
              g4 = bp2[kk-4], g5 = bp2[kk-5], g6 = bp2[kk-6], g7 = bp2[kk-7],\
              g8 = bp2[kk-8], g9 = bp2[kk-9];                                \
        BWP(0,p0,g0,FINF) BWP(1,p1,g1,FINF) BWP(2,p2,g2,FINF)                \
        BWP(3,p3,g3,FINF) BWP(4,p4,g4,FINF) BWP(5,p5,g5,FINF)                \
        BWP(6,p6,g6,FINF) BWP(7,p7,g7,FINF) BWP(8,p8,g8,FINF)                \
        BWP(9,p9,g9,FINF)                                                    \
        stB -= 10 * U_DIM;                                                   \
    }

#define BWC_BLOCK(FINF)                                                      \
    {                                                                        \
        const int tbk = tb2 + kk;                                            \
        float p0 = bb2[(kk-0)*LROW + L], p1 = bb2[(kk-1)*LROW + L],          \
              p2 = bb2[(kk-2)*LROW + L], p3 = bb2[(kk-3)*LROW + L],          \
              p4 = bb2[(kk-4)*LROW + L], p5 = bb2[(kk-5)*LROW + L],          \
              p6 = bb2[(kk-6)*LROW + L], p7 = bb2[(kk-7)*LROW + L],          \
              p8 = bb2[(kk-8)*LROW + L], p9 = bb2[(kk-9)*LROW + L];          \
        float g0 = bp2[kk-0], g1 = bp2[kk-1], g2 = bp2[kk-2], g3 = bp2[kk-3],\
              g4 = bp2[kk-4], g5 = bp2[kk-5], g6 = bp2[kk-6], g7 = bp2[kk-7],\
              g8 = bp2[kk-8], g9 = bp2[kk-9];                                \
        BWC(0,p0,g0,FINF) BWC(1,p1,g1,FINF) BWC(2,p2,g2,FINF)                \
        BWC(3,p3,g3,FINF) BWC(4,p4,g4,FINF) BWC(5,p5,g5,FINF)                \
        BWC(6,p6,g6,FINF) BWC(7,p7,g7,FINF) BWC(8,p8,g8,FINF)                \
        BWC(9,p9,g9,FINF)                                                    \
        stB -= 10 * U_DIM;                                                   \
    }

// ---- fused: 4 scan waves (2 per direction, LDS relay) + 12 loader waves ----
extern "C" __global__ void __launch_bounds__(1024)
brctc_fused(const float* __restrict__ nnet, const int* __restrict__ ys,
            const int* __restrict__ hlens, const int* __restrict__ ylens,
            float* __restrict__ P,
            float* __restrict__ A, float* __restrict__ Braw,
            float* __restrict__ out)
{
    const int b = blockIdx.x;
    const int tid = threadIdx.x;
    const int w = tid >> 6, L = tid & 63;
    const int hl = hlens[b], yl = ylens[b];
    const int hl1 = hl - 1;
    const size_t TP = T_DIM + 2 * PAD;
    const float* nb = nnet + (size_t)b * T_DIM * C_DIM;
    float* Pw = P + ((size_t)b * TP + PAD) * U_DIM;   // rows 0..T (+tail pad)
    const float* Pb = Pw;                             // loss-phase reads
    const int* ysb = ys + b * U_DIM;
    float* Ab = A    + (size_t)b * AROWS * U_DIM;
    float* Bb = Braw + (size_t)b * AROWS * U_DIM;

    __shared__ __align__(16) float fbuf[2][50 * LROW];
    __shared__ __align__(16) float bbuf[2][50 * LROW];
    __shared__ float fpb[2][56], bpb[2][56];
    __shared__ float shm[8][U_DIM], shs[8][U_DIM], shlu[U_DIM];
    __shared__ int shY[U_DIM];
    __shared__ __align__(8) float rlyF[64];   // 32 slots x (a99,a100)
    __shared__ float rlyB[32];                // 32 slots x q101
    __shared__ __align__(8) float dump[128];  // per-lane junk sink (64 x 8B)
    __shared__ int prgFC, prgBC;

    if (tid < U_DIM) shY[tid] = ysb[tid];

    volatile float* const dmp = (volatile float*)&dump[2 * L];

    // ---- per-lane scan constants (all threads compute; waves 0-3 use) ----
    const int cl = U_DIM - 1;
    const int yL   = ysb[min(L, cl)];
    const int yLm1 = ysb[min(max(L - 1, 0), cl)];
    const int yLp1 = ysb[min(L + 1, cl)];
    const int y50L = ysb[min(50 + L, cl)];
    const int y49L = ysb[min(49 + L, cl)];
    const int y51L = ysb[min(51 + L, cl)];
    const int ty = 2 * yl;
    const bool st = (L < 50);
    const float mzE_lo = (L <= 50 && 2 * L <= ty)       ? 0.0f : NEGINF;
    const float mzE_hi = (L <= 49 && 102 + 2 * L <= ty) ? 0.0f : NEGINF;
    const float mskFlo = (L >= 1 && yL != yLm1)  ? 0.0f : NEGINF;
    const float mskFhi = (y50L != y49L)          ? 0.0f : NEGINF;
    const float mskBhi = (L <= 48 && y51L != y50L) ? 0.0f : NEGINF;
    const float mskBlo = (yLp1 != yL)            ? 0.0f : NEGINF;
    const float fE_lo = (2*L     == ty || 2*L     == ty-1) ? 0.0f : NEGINF;
    const float fO_lo = (2*L+1   == ty || 2*L+1   == ty-1) ? 0.0f : NEGINF;
    const float fE_hi = (102+2*L == ty || 102+2*L == ty-1) ? 0.0f : NEGINF;
    const float fO_hi = (101+2*L == ty || 101+2*L == ty-1) ? 0.0f : NEGINF;

    float E0, O0, BE, BO;
    E0 = (w == 0 && L == 0) ? 0.0f : NEGINF;   // fwd-lo a[0]=0
    O0 = NEGINF; BE = NEGINF; BO = NEGINF;

    __syncthreads();   // shY ready for loaders

    // ---- prologue: ring init + pads + gather fwd chunk 0 / bwd chunk 19 ---
    if (w == 0) {
        if (L < 32) {
            rlyF[2*L]   = (L == 31) ? NEGINF : CANF;  // slot31 = a_{-1}[99,100]
            rlyF[2*L+1] = (L == 31) ? NEGINF : CANF;
            rlyB[L] = CANF;
        }
        if (L == 0) { prgFC = 0; prgBC = 0; }
    }
    if (w >= 4) {
        int j2 = tid - 256;                 // 0..767: -inf pads for all 4 bufs
        for (int i = j2; i < 4 * 50 * 28; i += 768) {
            int buf = i / (50 * 28), rem = i % (50 * 28);
            int r = rem / 28, q = 100 + rem % 28;
            float* base = (buf == 0) ? fbuf[0] : (buf == 1) ? fbuf[1]
                        : (buf == 2) ? bbuf[0] : bbuf[1];
            base[r * LROW + q] = NEGINF;
        }
    }
    if (w >= 4 && w < 10) {                // fwd loaders (waves 4..9, 384 thr)
        int j = tid - 256;
        gather_chunk(nb, shY, yl, fbuf[0], fpb[0], Pw, 0, j);
        if (j < U_DIM) Pw[(size_t)T_DIM * U_DIM + j] = NEGINF;  // P row 1000
    } else if (w >= 10) {                  // bwd loaders (waves 10..15)
        int j = tid - 640;
        gather_chunk(nb, shY, yl, bbuf[0], bpb[0], nullptr, 951, j);
    }
    __syncthreads();

    // ---- 20 chunks of 50 steps --------------------------------------------
    for (int c = 0; c < 20; ++c) {
        if (w == 0) {                       // FWD producer: states 0..100
            const float* fb = fbuf[c & 1];
            const float* fp = fpb[c & 1];
            const int tb = 50 * c;
            float* stA = Ab + (size_t)tb * U_DIM + L;
            for (int kk = 0; kk < 50; kk += 10) {
                if (tb + kk >= 30) {
                    const int need = tb + kk - 21;
                    while (*(volatile int*)&prgFC < need)
                        __builtin_amdgcn_s_sleep(8);
                    asm volatile("" ::: "memory");
                }
                const int tbk = tb + kk;
                float p0 = fb[(kk+0)*LROW + L], p1 = fb[(kk+1)*LROW + L],
                      p2 = fb[(kk+2)*LROW + L], p3 = fb[(kk+3)*LROW + L],
                      p4 = fb[(kk+4)*LROW + L], p5 = fb[(kk+5)*LROW + L],
                      p6 = fb[(kk+6)*LROW + L], p7 = fb[(kk+7)*LROW + L],
                      p8 = fb[(kk+8)*LROW + L], p9 = fb[(kk+9)*LROW + L];
                float g0 = fp[kk+0], g1 = fp[kk+1], g2 = fp[kk+2],
                      g3 = fp[kk+3], g4 = fp[kk+4], g5 = fp[kk+5],
                      g6 = fp[kk+6], g7 = fp[kk+7], g8 = fp[kk+8],
                      g9 = fp[kk+9];
                FWP(0,p0,g0) FWP(1,p1,g1) FWP(2,p2,g2) FWP(3,p3,g3)
                FWP(4,p4,g4) FWP(5,p5,g5) FWP(6,p6,g6) FWP(7,p7,g7)
                FWP(8,p8,g8) FWP(9,p9,g9)
                stA += 10 * U_DIM;
            }
        } else if (w == 1) {                // FWD consumer: states 101..200
            const float* fb = fbuf[c & 1];
            const float* fp = fpb[c & 1];
            const int tb = 50 * c;
            float* stA = Ab + (size_t)tb * U_DIM + 50 + L;
            for (int kk = 0; kk < 50; kk += 10) {
                const int tbk = tb + kk;
                float p0 = fb[(kk+0)*LROW + 50 + L], p1 = fb[(kk+1)*LROW + 50 + L],
                      p2 = fb[(kk+2)*LROW + 50 + L], p3 = fb[(kk+3)*LROW + 50 + L],
                      p4 = fb[(kk+4)*LROW + 50 + L], p5 = fb[(kk+5)*LROW + 50 + L],
                      p6 = fb[(kk+6)*LROW + 50 + L], p7 = fb[(kk+7)*LROW + 50 + L],
                      p8 = fb[(kk+8)*LROW + 50 + L], p9 = fb[(kk+9)*LROW + 50 + L];
                float g0 = fp[kk+0], g1 = fp[kk+1], g2 = fp[kk+2],
                      g3 = fp[kk+3], g4 = fp[kk+4], g5 = fp[kk+5],
                      g6 = fp[kk+6], g7 = fp[kk+7], g8 = fp[kk+8],
                      g9 = fp[kk+9];
                FWC(0,p0,g0) FWC(1,p1,g1) FWC(2,p2,g2) FWC(3,p3,g3)
                FWC(4,p4,g4) FWC(5,p5,g5) FWC(6,p6,g6) FWC(7,p7,g7)
                FWC(8,p8,g8) FWC(9,p9,g9)
                stA += 10 * U_DIM;
            }
        } else if (w == 2) {                // BWD producer: states 101..200
            const float* bb2 = bbuf[c & 1];
            const float* bp2 = bpb[c & 1];
            const int cc = 19 - c;
            const int tb2 = 50 * cc;
            float* stB = Bb + (size_t)(tb2 + 49) * U_DIM + 50 + L;
            if (hl1 >= tb2 && hl1 <= tb2 + 49) {
                for (int kk = 49; kk >= 9; kk -= 10) BWP_BLOCK(true)
            } else {
                for (int kk = 49; kk >= 9; kk -= 10) BWP_BLOCK(false)
            }
        } else if (w == 3) {                // BWD consumer: states 0..100
            const float* bb2 = bbuf[c & 1];
            const float* bp2 = bpb[c & 1];
            const int cc = 19 - c;
            const int tb2 = 50 * cc;
            float* stB = Bb + (size_t)(tb2 + 49) * U_DIM + L;
            if (hl1 >= tb2 && hl1 <= tb2 + 49) {
                for (int kk = 49; kk >= 9; kk -= 10) BWC_BLOCK(true)
            } else {
                for (int kk = 49; kk >= 9; kk -= 10) BWC_BLOCK(false)
            }
        } else if (c < 19) {                // loaders: gather next buffers
            if (w < 10) {
                int j = tid - 256;
                int row0 = (c + 1) * 50;                       // rows 50..950
                gather_chunk(nb, shY, yl, fbuf[(c + 1) & 1], fpb[(c + 1) & 1],
                             Pw + (size_t)row0 * U_DIM, row0, j);
            } else {
                int j = tid - 640;
                int row0 = (18 - c) * 50 + 1;                  // rows 1..901
                gather_chunk(nb, shY, yl, bbuf[(c + 1) & 1], bpb[(c + 1) & 1],
                             nullptr, row0, j);
            }
        }
        __syncthreads();
    }

    // sentinel row T = -inf (a_next at t = T-1 in loss phase)
    if (w == 0 && st)
        ((float2*)(Ab + (size_t)T_DIM * U_DIM))[L] = make_float2(NEGINF, NEGINF);

    // ---- post-fill: alpha rows >= hl are NEGINF ---------------------------
    {
        const int r0f = min(hl, T_DIM);
        const int nrow = T_DIM + 1 - r0f;
        const int tot = nrow * 50;
        for (int i = tid; i < tot; i += 1024) {
            const int rr = r0f + i / 50, cc2 = i % 50;
            ((float2*)(Ab + (size_t)rr * U_DIM))[cc2] = make_float2(NEGINF, NEGINF);
        }
    }
    __syncthreads();

    // ---- loss phase (verbatim r10 structure) ------------------------------
    {
        const int u = tid & 127;
        const int c = tid >> 7;               // 0..7
        if (u < U_DIM) {
            const bool valu = (u < yl);
            const float inv_hl = 1.0f / (float)hl;
            const int t0 = 125 * c;
            float a_t    = Ab[(size_t)t0 * U_DIM + u];
            float braw_t = Bb[(size_t)t0 * U_DIM + u];
            float aA0 = Ab[(long)(t0 + 1) * U_DIM + u];
            float aA1 = Ab[(long)(t0 + 2) * U_DIM + u];
            float aA2 = Ab[(long)(t0 + 3) * U_DIM + u];
            float aA3 = Ab[(long)(t0 + 4) * U_DIM + u];
            float bA0 = Bb[(long)(t0 + 1) * U_DIM + u];
            float bA1 = Bb[(long)(t0 + 2) * U_DIM + u];
            float bA2 = Bb[(long)(t0 + 3) * U_DIM + u];
            float bA3 = Bb[(long)(t0 + 4) * U_DIM + u];
            float pA0 = valu ? Pb[(long)(t0 + 1) * U_DIM + u] : NEGINF;
            float pA1 = valu ? Pb[(long)(t0 + 2) * U_DIM + u] : NEGINF;
            float pA2 = valu ? Pb[(long)(t0 + 3) * U_DIM + u] : NEGINF;
            float pA3 = valu ? Pb[(long)(t0 + 4) * U_DIM + u] : NEGINF;
            float m = NEGINF, ssum = 0.0f;
            for (int kb = 0; kb <= 120; kb += 4) {
                long nr = (long)(t0 + kb + 5);
                float aB0 = Ab[(nr + 0) * U_DIM + u];
                float aB1 = Ab[(nr + 1) * U_DIM + u];
                float aB2 = Ab[(nr + 2) * U_DIM + u];
                float aB3 = Ab[(nr + 3) * U_DIM + u];
                float bB0 = Bb[(nr + 0) * U_DIM + u];
                float bB1 = Bb[(nr + 1) * U_DIM + u];
                float bB2 = Bb[(nr + 2) * U_DIM + u];
                float bB3 = Bb[(nr + 3) * U_DIM + u];
                float pB0 = valu ? Pb[(nr + 0) * U_DIM + u] : NEGINF;
                float pB1 = valu ? Pb[(nr + 1) * U_DIM + u] : NEGINF;
                float pB2 = valu ? Pb[(nr + 2) * U_DIM + u] : NEGINF;
                float pB3 = valu ? Pb[(nr + 3) * U_DIM + u] : NEGINF;
                LSTEP(t0 + kb + 0, aA0, bA0, pA0)
                LSTEP(t0 + kb + 1, aA1, bA1, pA1)
                LSTEP(t0 + kb + 2, aA2, bA2, pA2)
                LSTEP(t0 + kb + 3, aA3, bA3, pA3)
                aA0 = aB0; aA1 = aB1; aA2 = aB2; aA3 = aB3;
                bA0 = bB0; bA1 = bB1; bA2 = bB2; bA3 = bB3;
                pA0 = pB0; pA1 = pB1; pA2 = pB2; pA3 = pB3;
            }
            LSTEP(t0 + 124, aA0, bA0, pA0)
            shm[c][u] = m; shs[c][u] = ssum;
        }
    }
    __syncthreads();
    if (tid < U_DIM) {
        float M = NEGINF;
#pragma unroll
        for (int c = 0; c < 8; ++c) M = fmaxf(M, shm[c][tid]);
        float lu = NEGINF;
        if (M != NEGINF) {
            float s = 0.0f;
#pragma unroll
            for (int c = 0; c < 8; ++c) {
                float mc = shm[c][tid];
                if (mc != NEGINF) s += shs[c][tid] * __expf(mc - M);
            }
            lu = M + __logf(s);
        }
        shlu[tid] = lu;
    }
    __syncthreads();
    if (tid == 0) {
        int cnt = 0;
        for (int u = 0; u < U_DIM; ++u) cnt += (shlu[u] != NEGINF) ? 1 : 0;
        int last = cnt - 1;
        last = last < 0 ? 0 : (last > U_DIM - 1 ? U_DIM - 1 : last);
        out[b] = -shlu[last];
    }
}

// =================== fallback (small ws): round-1-style direct path =========
extern "C" __global__ void __launch_bounds__(256)
brctc_fwd_fb(const float* __restrict__ nnet, const int* __restrict__ ys,
             const int* __restrict__ hlens, const int* __restrict__ ylens,
             float* __restrict__ a_l)
{
    const int b = blockIdx.x;
    const int s = threadIdx.x;
    __shared__ float sh_a[201];
    __shared__ int   sh_ys[U_DIM];
    if (s < U_DIM) sh_ys[s] = ys[b * U_DIM + s];
    __syncthreads();
    const int hl = hlens[b], yl = ylens[b];
    int lab = 0; bool skip = false;
    if (s < 201) {
        if (s & 1) lab = sh_ys[(s - 1) >> 1];
        if ((s & 1) && s >= 3) skip = (sh_ys[(s - 1) >> 1] != sh_ys[(s - 3) >> 1]);
        sh_a[s] = (s == 0) ? 0.0f : NEGINF;
    }
    const bool valid = (s < 201) && (s <= 2 * yl);
    const bool isodd = (s < 201) && (s & 1);
    const int l = (s - 1) >> 1;
    const float* base = nnet + (size_t)b * T_DIM * C_DIM;
    float* alb = a_l + (size_t)b * T_DIM * U_DIM;
    __syncthreads();
    float p_cur = valid ? base[lab] : NEGINF;
    for (int t = 0; t < T_DIM; ++t) {
        float p_nxt = (valid && (t + 1 < T_DIM)) ? base[(size_t)(t + 1) * C_DIM + lab] : NEGINF;
        float x1 = (s < 201) ? sh_a[s] : NEGINF;
        float x2 = (s >= 1 && s < 201) ? sh_a[s - 1] : NEGINF;
        float x3 = skip ? sh_a[s - 2] : NEGINF;
        float anew = p_cur + lse3f(x1, x2, x3);
        __syncthreads();
        if (s < 201) sh_a[s] = anew;
        if (isodd) alb[t * U_DIM + l] = (t < hl) ? anew : NEGINF;
        __syncthreads();
        p_cur = p_nxt;
    }
}

extern "C" __global__ void __launch_bounds__(256)
brctc_bwd_fb(const float* __restrict__ nnet, const int* __restrict__ ys,
             const int* __restrict__ hlens, const int* __restrict__ ylens,
             const float* __restrict__ a_l, float* __restrict__ out)
{
    const int b = blockIdx.x;
    const int s = threadIdx.x;
    __shared__ float sh_b[201], sh_q[201], sh_lu[U_DIM];
    __shared__ int sh_ys[U_DIM];
    if (s < U_DIM) sh_ys[s] = ys[b * U_DIM + s];
    __syncthreads();
    const int hl = hlens[b], yl = ylens[b];
    int lab = 0; bool skip2 = false;
    if (s < 201) {
        if (s & 1) lab = sh_ys[(s - 1) >> 1];
        int s2 = s + 2;
        if (s2 < 201 && (s2 & 1) && s2 >= 3)
            skip2 = (sh_ys[(s2 - 1) >> 1] != sh_ys[(s2 - 3) >> 1]);
        sh_b[s] = NEGINF;
    }
    const bool valid = (s < 201) && (s <= 2 * yl);
    const bool isodd = (s < 201) && (s & 1);
    const int l = (s - 1) >> 1;
    const float fin0 = (s == 2 * yl || s == 2 * yl - 1) ? 0.0f : NEGINF;
    const float* base = nnet + (size_t)b * T_DIM * C_DIM;
    const float* alb = a_l + (size_t)b * T_DIM * U_DIM;
    float m_run = NEGINF, acc = 0.0f, prev_bl = NEGINF, p_hi = NEGINF;
    __syncthreads();
    for (int t = T_DIM - 1; t >= 0; --t) {
        float p_lo = valid ? base[(size_t)t * C_DIM + lab] : NEGINF;
        float a_cur = isodd ? alb[t * U_DIM + l] : NEGINF;
        float q = (s < 201) ? (p_hi + sh_b[s]) : NEGINF;
        if (s < 201) sh_q[s] = q;
        __syncthreads();
        float q2 = (s + 1 < 201) ? sh_q[s + 1] : NEGINF;
        float q3 = skip2 ? sh_q[s + 2] : NEGINF;
        float cand = lse3f(q, q2, q3);
        float bnew = (t == hl - 1) ? fin0 : cand;
        if (s < 201) sh_b[s] = bnew;
        if (isodd) {
            float bl_t = (a_cur == NEGINF) ? NEGINF : bnew;
            float bp = (t == T_DIM - 1) ? bl_t : log_sub_expf(bl_t, prev_bl + p_hi);
            float x = a_cur + bp - 0.1f * ((float)t / (float)hl);
            if (x != NEGINF) {
                if (x <= m_run) acc += __expf(x - m_run);
                else { acc = acc * __expf(m_run - x) + 1.0f; m_run = x; }
            }
            prev_bl = bl_t;
        }
        __syncthreads();
        p_hi = p_lo;
    }
    if (isodd) sh_lu[l] = (m_run == NEGINF) ? NEGINF : (m_run + __logf(acc));
    __syncthreads();
    if (s == 0) {
        int cnt = 0;
        for (int u = 0; u < U_DIM; ++u) cnt += (sh_lu[u] != NEGINF) ? 1 : 0;
        int last = cnt - 1;
        last = last < 0 ? 0 : (last > U_DIM - 1 ? U_DIM - 1 : last);
        out[b] = -sh_lu[last];
    }
}

extern "C" void kernel_launch(void* const* d_in, const int* in_sizes, int n_in,
                              void* d_out, int out_size, void* d_ws, size_t ws_size,
                              hipStream_t stream) {
    const float* nnet  = (const float*)d_in[0];
    const int*   ys    = (const int*)d_in[1];
    const int*   hlens = (const int*)d_in[2];
    const int*   ylens = (const int*)d_in[3];
    float*       outp  = (float*)d_out;
    const int B = in_sizes[2];
    const size_t TP = T_DIM + 2 * PAD;
    const size_t szP  = (size_t)B * TP * U_DIM;
    const size_t szA  = (size_t)B * AROWS * U_DIM;
    const size_t need = (szP + 2 * szA) * sizeof(float);

    if (ws_size >= need) {
        float* P    = (float*)d_ws;
        float* A    = P + szP;
        float* Braw = A + szA;
        brctc_fused<<<B, 1024, 0, stream>>>(nnet, ys, hlens, ylens, P, A, Braw, outp);
    } else {
        float* A = (float*)d_ws;
        brctc_fwd_fb<<<B, 256, 0, stream>>>(nnet, ys, hlens, ylens, A);
        brctc_bwd_fb<<<B, 256, 0, stream>>>(nnet, ys, hlens, ylens, A, outp);
    }
}

// Round 5
// 368.349 us; speedup vs baseline: 1.5132x; 1.5132x over previous
//
#include <hip/hip_runtime.h>
#include <math.h>

#define T_DIM 1000
#define C_DIM 500
#define U_DIM 100
#define PAD   16          // head/tail padding rows for P
#define AROWS (T_DIM + 5) // A/Braw rows (loss pipeline reads to row T+4)
#define NEGINF (-INFINITY)
#define LROW  128         // LDS row stride in floats; cols 100..127 = -inf pad

// ---- scalar lse helpers: bit-identical to reference op order (validated
// rounds r1-r4, absmax 0.0).  All-dead case -> NaN -> fmaxf(r,-inf) = -inf.
__device__ __forceinline__ float lse2s(float a, float b) {
    float m = fmaxf(a, b), mn = fminf(a, b);
    float r = m + __logf(1.0f + __expf(mn - m));
    return fmaxf(r, NEGINF);
}
__device__ __forceinline__ float lse3s(float x1, float x2, float x3) {
    float m = fmaxf(fmaxf(x1, x2), x3);
    float r = m + __logf(__expf(x1 - m) + __expf(x2 - m) + __expf(x3 - m));
    return fmaxf(r, NEGINF);
}
// scalar lse3 for the fallback kernels (original guard form)
__device__ __forceinline__ float lse3f(float x1, float x2, float x3) {
    float m = fmaxf(fmaxf(x1, x2), x3);
    if (m == NEGINF) return NEGINF;
    return m + __logf(__expf(x1 - m) + __expf(x2 - m) + __expf(x3 - m));
}

// Bug-compatible replica of reference _log_sub_exp (incl. inf-substitution quirk).
__device__ __forceinline__ float log_sub_expf(float a, float b) {
    bool ia = isinf(a), ib = isinf(b);
    if (!ia && !ib) {
        float ans = b + __logf(__expf(a - b) - 1.0f);
        if (isinf(ans)) ans = -2001.0f + __logf(__expf(1.0f) - 1.0f);
        return ans;
    }
    if (!ia && ib) return a;
    return NEGINF;
}

// DPP lane shifts (validated bit-exact rounds 6-10)
__device__ __forceinline__ float dpp_shr1(float x) {  // lane L <- L-1; lane0 <- -inf
    int r = __builtin_amdgcn_update_dpp(__float_as_int(NEGINF), __float_as_int(x),
                                        0x138, 0xF, 0xF, false);  // wave_shr:1
    return __int_as_float(r);
}
__device__ __forceinline__ float dpp_shl1(float x) {  // lane L <- L+1; lane63 <- -inf
    int r = __builtin_amdgcn_update_dpp(__float_as_int(NEGINF), __float_as_int(x),
                                        0x130, 0xF, 0xF, false);  // wave_shl:1
    return __int_as_float(r);
}

// ---- loss step (verbatim r10) ----------------------------------------------
#define LSTEP(tt, RA, RB, RP)                                                \
    {                                                                        \
        float a_nx = (RA), br_nx = (RB), p_nx = (RP);                        \
        float bl   = (a_t  == NEGINF) ? NEGINF : braw_t;                     \
        float term = (a_nx == NEGINF) ? NEGINF : (br_nx + p_nx);             \
        float bp = log_sub_expf(bl, term);                                   \
        float x = a_t + bp - 0.1f * (float)(tt) * inv_hl;                    \
        if (x != NEGINF) {                                                   \
            float nm = fmaxf(m, x);                                          \
            ssum = ssum * __expf(m - nm) + __expf(x - nm);                   \
            m = nm;                                                          \
        }                                                                    \
        a_t = a_nx; braw_t = br_nx;                                          \
    }

// ---- loader gather: 50 rows x (100 labels + blank) straight from nnet ------
__device__ __forceinline__ void gather_chunk(
    const float* __restrict__ nb, const int* __restrict__ shY, int yl,
    float* __restrict__ lds, float* __restrict__ ldsb,
    float* __restrict__ Pg /* global row0 base, or nullptr */,
    int row0, int j)
{
#pragma unroll
    for (int k = 0; k < 17; ++k) {
        int i = j + k * 384;                 // 384 loader threads per direction
        if (i < 6400) {                      // 50 rows x 128 slots
            int r = i >> 7, q = i & 127;
            if (q <= 100) {
                int row = row0 + r;
                int col = (q < 100) ? shY[q] : 0;
                float v = (row < T_DIM) ? nb[(size_t)row * C_DIM + col] : NEGINF;
                if (q < 100) {
                    lds[r * LROW + q] = (q < yl) ? v : NEGINF;
                    if (Pg) Pg[(size_t)r * U_DIM + q] = v;
                } else {
                    ldsb[r] = v;
                }
            }
        }
    }
}

// ======================= scan step macros (2 states/lane) ===================
// Arithmetic is verbatim r4 (HW-validated bit-exact, absmax 0.0); only the
// relay/synchronization changed: block-granular progress counter, masked
// single-lane relay stores, batched plain ds_reads on the consumer.

// FWD producer (states 0..100; lane L: E=s2L, O=s2L+1; lane50 O dead):
#define FWP(j, pOv, gv)                                                      \
    {                                                                        \
        float Osh = dpp_shr1(O0);                                            \
        float nE = (mzE_lo + (gv)) + lse2s(E0, Osh);                         \
        float nO = (pOv) + lse3s(O0, E0, Osh + mskFlo);                      \
        float nOsh = dpp_shr1(nO);                                           \
        if (L == 50)                                                         \
            ((float2*)rlyF)[(tbk + (j)) & 63] = make_float2(nOsh, nE);       \
        E0 = nE; O0 = nO;                                                    \
        if (st) stA[(j) * U_DIM] = nO;                                       \
    }

// FWD consumer (states 101..200; lane L: O=s101+2L, E=s102+2L):
#define FWC(j, pOv, gv, rv)                                                  \
    {                                                                        \
        float Esh = dpp_shr1(E0); Esh = (L == 0) ? (rv).y : Esh;             \
        float Osh = dpp_shr1(O0); Osh = (L == 0) ? (rv).x : Osh;             \
        float nE = (mzE_hi + (gv)) + lse2s(E0, O0);                          \
        float nO = (pOv) + lse3s(O0, Esh, Osh + mskFhi);                     \
        E0 = nE; O0 = nO;                                                    \
        if (st) stA[(j) * U_DIM] = nO;                                       \
    }

// BWD producer (states 101..200): relay q[101] (lane0 qO) early each step.
#define BWP(j, pOv, gv, FINF)                                                \
    {                                                                        \
        const int t_ = tbk - (j);                                            \
        float qE = (mzE_hi + (gv)) + BE;                                     \
        float qO = (pOv) + BO;                                               \
        if (L == 0) rlyB[(999 - t_) & 63] = qO;                              \
        float qOsh = dpp_shl1(qO);                                           \
        float nE = lse2s(qE, qOsh);                                          \
        float nO = lse3s(qO, qE, qOsh + mskBhi);                             \
        if (FINF) { const bool fin = (t_ == hl1);                            \
            BE = fin ? fE_hi : nE; BO = fin ? fO_hi : nO;                    \
        } else { BE = nE; BO = nO; }                                         \
        if (st) stB[-(int)((j) * U_DIM)] = BO;                               \
    }

// BWD consumer (states 0..100): inject relayed q[101] at lane50's qO.
#define BWC(j, pOv, gv, FINF, rq)                                            \
    {                                                                        \
        const int t_ = tbk - (j);                                            \
        float qE = (mzE_lo + (gv)) + BE;                                     \
        float qO = (pOv) + BO;                                               \
        qO = (L == 50) ? (rq) : qO;                                          \
        float qEsh = dpp_shl1(qE);                                           \
        float qOsh = dpp_shl1(qO);                                           \
        float nE = lse2s(qE, qO);                                            \
        float nO = lse3s(qO, qEsh, qOsh + mskBlo);                           \
        if (FINF) { const bool fin = (t_ == hl1);                            \
            BE = fin ? fE_lo : nE; BO = fin ? fO_lo : nO;                    \
        } else { BE = nE; BO = nO; }                                         \
        if (st) stB[-(int)((j) * U_DIM)] = BO;                               \
    }

#define BWP_BLOCK(FINF)                                                      \
    {                                                                        \
        const int tbk = tb2 + kk;                                            \
        float p0 = bb2[(kk-0)*LROW + 50 + L], p1 = bb2[(kk-1)*LROW + 50 + L],\
              p2 = bb2[(kk-2)*LROW + 50 + L], p3 = bb2[(kk-3)*LROW + 50 + L],\
              p4 = bb2[(kk-4)*LROW + 50 + L], p5 = bb2[(kk-5)*LROW + 50 + L],\
              p6 = bb2[(kk-6)*LROW + 50 + L], p7 = bb2[(kk-7)*LROW + 50 + L],\
              p8 = bb2[(kk-8)*LROW + 50 + L], p9 = bb2[(kk-9)*LROW + 50 + L];\
        float g0 = bp2[kk-0], g1 = bp2[kk-1], g2 = bp2[kk-2], g3 = bp2[kk-3],\
              g4 = bp2[kk-4], g5 = bp2[kk-5], g6 = bp2[kk-6], g7 = bp2[kk-7],\
              g8 = bp2[kk-8], g9 = bp2[kk-9];                                \
        BWP(0,p0,g0,FINF) BWP(1,p1,g1,FINF) BWP(2,p2,g2,FINF)                \
        BWP(3,p3,g3,FINF) BWP(4,p4,g4,FINF) BWP(5,p5,g5,FINF)                \
        BWP(6,p6,g6,FINF) BWP(7,p7,g7,FINF) BWP(8,p8,g8,FINF)                \
        BWP(9,p9,g9,FINF)                                                    \
        asm volatile("s_waitcnt lgkmcnt(0)" ::: "memory");                   \
        if (L == 0) *(volatile int*)&prgB = (999 - tbk) + 10;                \
        stB -= 10 * U_DIM;                                                   \
    }

#define BWC_BLOCK(FINF)                                                      \
    {                                                                        \
        const int tbk = tb2 + kk;                                            \
        const int kb = 999 - tbk;                                            \
        while (*(volatile int*)&prgB < kb + 10)                              \
            __builtin_amdgcn_s_sleep(1);                                     \
        asm volatile("" ::: "memory");                                       \
        float q0 = rlyB[(kb+0)&63], q1 = rlyB[(kb+1)&63],                    \
              q2 = rlyB[(kb+2)&63], q3 = rlyB[(kb+3)&63],                    \
              q4 = rlyB[(kb+4)&63], q5 = rlyB[(kb+5)&63],                    \
              q6 = rlyB[(kb+6)&63], q7 = rlyB[(kb+7)&63],                    \
              q8 = rlyB[(kb+8)&63], q9 = rlyB[(kb+9)&63];                    \
        float p0 = bb2[(kk-0)*LROW + L], p1 = bb2[(kk-1)*LROW + L],          \
              p2 = bb2[(kk-2)*LROW + L], p3 = bb2[(kk-3)*LROW + L],          \
              p4 = bb2[(kk-4)*LROW + L], p5 = bb2[(kk-5)*LROW + L],          \
              p6 = bb2[(kk-6)*LROW + L], p7 = bb2[(kk-7)*LROW + L],          \
              p8 = bb2[(kk-8)*LROW + L], p9 = bb2[(kk-9)*LROW + L];          \
        float g0 = bp2[kk-0], g1 = bp2[kk-1], g2 = bp2[kk-2], g3 = bp2[kk-3],\
              g4 = bp2[kk-4], g5 = bp2[kk-5], g6 = bp2[kk-6], g7 = bp2[kk-7],\
              g8 = bp2[kk-8], g9 = bp2[kk-9];                                \
        BWC(0,p0,g0,FINF,q0) BWC(1,p1,g1,FINF,q1) BWC(2,p2,g2,FINF,q2)       \
        BWC(3,p3,g3,FINF,q3) BWC(4,p4,g4,FINF,q4) BWC(5,p5,g5,FINF,q5)       \
        BWC(6,p6,g6,FINF,q6) BWC(7,p7,g7,FINF,q7) BWC(8,p8,g8,FINF,q8)       \
        BWC(9,p9,g9,FINF,q9)                                                 \
        stB -= 10 * U_DIM;                                                   \
    }

// ---- fused: 4 scan waves (2 per direction, LDS relay) + 12 loader waves ----
extern "C" __global__ void __launch_bounds__(1024)
brctc_fused(const float* __restrict__ nnet, const int* __restrict__ ys,
            const int* __restrict__ hlens, const int* __restrict__ ylens,
            float* __restrict__ P,
            float* __restrict__ A, float* __restrict__ Braw,
            float* __restrict__ out)
{
    const int b = blockIdx.x;
    const int tid = threadIdx.x;
    const int w = tid >> 6, L = tid & 63;
    const int hl = hlens[b], yl = ylens[b];
    const int hl1 = hl - 1;
    const size_t TP = T_DIM + 2 * PAD;
    const float* nb = nnet + (size_t)b * T_DIM * C_DIM;
    float* Pw = P + ((size_t)b * TP + PAD) * U_DIM;   // rows 0..T (+tail pad)
    const float* Pb = Pw;                             // loss-phase reads
    const int* ysb = ys + b * U_DIM;
    float* Ab = A    + (size_t)b * AROWS * U_DIM;
    float* Bb = Braw + (size_t)b * AROWS * U_DIM;

    __shared__ __align__(16) float fbuf[2][50 * LROW];
    __shared__ __align__(16) float bbuf[2][50 * LROW];
    __shared__ float fpb[2][56], bpb[2][56];
    __shared__ float shm[8][U_DIM], shs[8][U_DIM], shlu[U_DIM];
    __shared__ int shY[U_DIM];
    __shared__ __align__(8) float rlyF[128];  // 64 slots x (a99,a100)
    __shared__ float rlyB[64];                // 64 slots x q101
    __shared__ int prgF, prgB;

    if (tid < U_DIM) shY[tid] = ysb[tid];

    // ---- per-lane scan constants (all threads compute; waves 0-3 use) ----
    const int cl = U_DIM - 1;
    const int yL   = ysb[min(L, cl)];
    const int yLm1 = ysb[min(max(L - 1, 0), cl)];
    const int yLp1 = ysb[min(L + 1, cl)];
    const int y50L = ysb[min(50 + L, cl)];
    const int y49L = ysb[min(49 + L, cl)];
    const int y51L = ysb[min(51 + L, cl)];
    const int ty = 2 * yl;
    const bool st = (L < 50);
    const float mzE_lo = (L <= 50 && 2 * L <= ty)       ? 0.0f : NEGINF;
    const float mzE_hi = (L <= 49 && 102 + 2 * L <= ty) ? 0.0f : NEGINF;
    const float mskFlo = (L >= 1 && yL != yLm1)  ? 0.0f : NEGINF;
    const float mskFhi = (y50L != y49L)          ? 0.0f : NEGINF;
    const float mskBhi = (L <= 48 && y51L != y50L) ? 0.0f : NEGINF;
    const float mskBlo = (yLp1 != yL)            ? 0.0f : NEGINF;
    const float fE_lo = (2*L     == ty || 2*L     == ty-1) ? 0.0f : NEGINF;
    const float fO_lo = (2*L+1   == ty || 2*L+1   == ty-1) ? 0.0f : NEGINF;
    const float fE_hi = (102+2*L == ty || 102+2*L == ty-1) ? 0.0f : NEGINF;
    const float fO_hi = (101+2*L == ty || 101+2*L == ty-1) ? 0.0f : NEGINF;

    float E0, O0, BE, BO;
    E0 = (w == 0 && L == 0) ? 0.0f : NEGINF;   // fwd-lo a[0]=0
    O0 = NEGINF; BE = NEGINF; BO = NEGINF;

    __syncthreads();   // shY ready for loaders

    // ---- prologue: ring/progress init + pads + gather first chunks --------
    if (w == 0 && L == 0) {
        prgF = 0; prgB = 0;
        ((float2*)rlyF)[63] = make_float2(NEGINF, NEGINF);  // a_{-1}[99,100]
    }
    if (w >= 4) {
        int j2 = tid - 256;                 // 0..767: -inf pads for all 4 bufs
        for (int i = j2; i < 4 * 50 * 28; i += 768) {
            int buf = i / (50 * 28), rem = i % (50 * 28);
            int r = rem / 28, q = 100 + rem % 28;
            float* base = (buf == 0) ? fbuf[0] : (buf == 1) ? fbuf[1]
                        : (buf == 2) ? bbuf[0] : bbuf[1];
            base[r * LROW + q] = NEGINF;
        }
    }
    if (w >= 4 && w < 10) {                // fwd loaders (waves 4..9, 384 thr)
        int j = tid - 256;
        gather_chunk(nb, shY, yl, fbuf[0], fpb[0], Pw, 0, j);
        if (j < U_DIM) Pw[(size_t)T_DIM * U_DIM + j] = NEGINF;  // P row 1000
    } else if (w >= 10) {                  // bwd loaders (waves 10..15)
        int j = tid - 640;
        gather_chunk(nb, shY, yl, bbuf[0], bpb[0], nullptr, 951, j);
    }
    __syncthreads();

    // ---- 20 chunks of 50 steps --------------------------------------------
    for (int c = 0; c < 20; ++c) {
        if (w == 0) {                       // FWD producer: states 0..100
            const float* fb = fbuf[c & 1];
            const float* fp = fpb[c & 1];
            const int tb = 50 * c;
            float* stA = Ab + (size_t)tb * U_DIM + L;
            for (int kk = 0; kk < 50; kk += 10) {
                const int tbk = tb + kk;
                float p0 = fb[(kk+0)*LROW + L], p1 = fb[(kk+1)*LROW + L],
                      p2 = fb[(kk+2)*LROW + L], p3 = fb[(kk+3)*LROW + L],
                      p4 = fb[(kk+4)*LROW + L], p5 = fb[(kk+5)*LROW + L],
                      p6 = fb[(kk+6)*LROW + L], p7 = fb[(kk+7)*LROW + L],
                      p8 = fb[(kk+8)*LROW + L], p9 = fb[(kk+9)*LROW + L];
                float g0 = fp[kk+0], g1 = fp[kk+1], g2 = fp[kk+2],
                      g3 = fp[kk+3], g4 = fp[kk+4], g5 = fp[kk+5],
                      g6 = fp[kk+6], g7 = fp[kk+7], g8 = fp[kk+8],
                      g9 = fp[kk+9];
                FWP(0,p0,g0) FWP(1,p1,g1) FWP(2,p2,g2) FWP(3,p3,g3)
                FWP(4,p4,g4) FWP(5,p5,g5) FWP(6,p6,g6) FWP(7,p7,g7)
                FWP(8,p8,g8) FWP(9,p9,g9)
                asm volatile("s_waitcnt lgkmcnt(0)" ::: "memory");
                if (L == 0) *(volatile int*)&prgF = tbk + 10;
                stA += 10 * U_DIM;
            }
        } else if (w == 1) {                // FWD consumer: states 101..200
            const float* fb = fbuf[c & 1];
            const float* fp = fpb[c & 1];
            const int tb = 50 * c;
            float* stA = Ab + (size_t)tb * U_DIM + 50 + L;
            for (int kk = 0; kk < 50; kk += 10) {
                const int tbk = tb + kk;
                while (*(volatile int*)&prgF < tbk + 9)
                    __builtin_amdgcn_s_sleep(1);
                asm volatile("" ::: "memory");
                const float2* rf = (const float2*)rlyF;
                float2 v0 = rf[(tbk + 63) & 63], v1 = rf[(tbk + 0) & 63],
                       v2 = rf[(tbk + 1) & 63],  v3 = rf[(tbk + 2) & 63],
                       v4 = rf[(tbk + 3) & 63],  v5 = rf[(tbk + 4) & 63],
                       v6 = rf[(tbk + 5) & 63],  v7 = rf[(tbk + 6) & 63],
                       v8 = rf[(tbk + 7) & 63],  v9 = rf[(tbk + 8) & 63];
                float p0 = fb[(kk+0)*LROW + 50 + L], p1 = fb[(kk+1)*LROW + 50 + L],
                      p2 = fb[(kk+2)*LROW + 50 + L], p3 = fb[(kk+3)*LROW + 50 + L],
                      p4 = fb[(kk+4)*LROW + 50 + L], p5 = fb[(kk+5)*LROW + 50 + L],
                      p6 = fb[(kk+6)*LROW + 50 + L], p7 = fb[(kk+7)*LROW + 50 + L],
                      p8 = fb[(kk+8)*LROW + 50 + L], p9 = fb[(kk+9)*LROW + 50 + L];
                float g0 = fp[kk+0], g1 = fp[kk+1], g2 = fp[kk+2],
                      g3 = fp[kk+3], g4 = fp[kk+4], g5 = fp[kk+5],
                      g6 = fp[kk+6], g7 = fp[kk+7], g8 = fp[kk+8],
                      g9 = fp[kk+9];
                FWC(0,p0,g0,v0) FWC(1,p1,g1,v1) FWC(2,p2,g2,v2) FWC(3,p3,g3,v3)
                FWC(4,p4,g4,v4) FWC(5,p5,g5,v5) FWC(6,p6,g6,v6) FWC(7,p7,g7,v7)
                FWC(8,p8,g8,v8) FWC(9,p9,g9,v9)
                stA += 10 * U_DIM;
            }
        } else if (w == 2) {                // BWD producer: states 101..200
            const float* bb2 = bbuf[c & 1];
            const float* bp2 = bpb[c & 1];
            const int cc = 19 - c;
            const int tb2 = 50 * cc;
            float* stB = Bb + (size_t)(tb2 + 49) * U_DIM + 50 + L;
            if (hl1 >= tb2 && hl1 <= tb2 + 49) {
                for (int kk = 49; kk >= 9; kk -= 10) BWP_BLOCK(true)
            } else {
                for (int kk = 49; kk >= 9; kk -= 10) BWP_BLOCK(false)
            }
        } else if (w == 3) {                // BWD consumer: states 0..100
            const float* bb2 = bbuf[c & 1];
            const float* bp2 = bpb[c & 1];
            const int cc = 19 - c;
            const int tb2 = 50 * cc;
            float* stB = Bb + (size_t)(tb2 + 49) * U_DIM + L;
            if (hl1 >= tb2 && hl1 <= tb2 + 49) {
                for (int kk = 49; kk >= 9; kk -= 10) BWC_BLOCK(true)
            } else {
                for (int kk = 49; kk >= 9; kk -= 10) BWC_BLOCK(false)
            }
        } else if (c < 19) {                // loaders: gather next buffers
            if (w < 10) {
                int j = tid - 256;
                int row0 = (c + 1) * 50;                       // rows 50..950
                gather_chunk(nb, shY, yl, fbuf[(c + 1) & 1], fpb[(c + 1) & 1],
                             Pw + (size_t)row0 * U_DIM, row0, j);
            } else {
                int j = tid - 640;
                int row0 = (18 - c) * 50 + 1;                  // rows 1..901
                gather_chunk(nb, shY, yl, bbuf[(c + 1) & 1], bpb[(c + 1) & 1],
                             nullptr, row0, j);
            }
        }
        __syncthreads();
    }

    // sentinel row T = -inf (a_next at t = T-1 in loss phase)
    if (w == 0 && st)
        ((float2*)(Ab + (size_t)T_DIM * U_DIM))[L] = make_float2(NEGINF, NEGINF);

    // ---- post-fill: alpha rows >= hl are NEGINF ---------------------------
    {
        const int r0f = min(hl, T_DIM);
        const int nrow = T_DIM + 1 - r0f;
        const int tot = nrow * 50;
        for (int i = tid; i < tot; i += 1024) {
            const int rr = r0f + i / 50, cc2 = i % 50;
            ((float2*)(Ab + (size_t)rr * U_DIM))[cc2] = make_float2(NEGINF, NEGINF);
        }
    }
    __syncthreads();

    // ---- loss phase (verbatim r10 structure) ------------------------------
    {
        const int u = tid & 127;
        const int c = tid >> 7;               // 0..7
        if (u < U_DIM) {
            const bool valu = (u < yl);
            const float inv_hl = 1.0f / (float)hl;
            const int t0 = 125 * c;
            float a_t    = Ab[(size_t)t0 * U_DIM + u];
            float braw_t = Bb[(size_t)t0 * U_DIM + u];
            float aA0 = Ab[(long)(t0 + 1) * U_DIM + u];
            float aA1 = Ab[(long)(t0 + 2) * U_DIM + u];
            float aA2 = Ab[(long)(t0 + 3) * U_DIM + u];
            float aA3 = Ab[(long)(t0 + 4) * U_DIM + u];
            float bA0 = Bb[(long)(t0 + 1) * U_DIM + u];
            float bA1 = Bb[(long)(t0 + 2) * U_DIM + u];
            float bA2 = Bb[(long)(t0 + 3) * U_DIM + u];
            float bA3 = Bb[(long)(t0 + 4) * U_DIM + u];
            float pA0 = valu ? Pb[(long)(t0 + 1) * U_DIM + u] : NEGINF;
            float pA1 = valu ? Pb[(long)(t0 + 2) * U_DIM + u] : NEGINF;
            float pA2 = valu ? Pb[(long)(t0 + 3) * U_DIM + u] : NEGINF;
            float pA3 = valu ? Pb[(long)(t0 + 4) * U_DIM + u] : NEGINF;
            float m = NEGINF, ssum = 0.0f;
            for (int kb = 0; kb <= 120; kb += 4) {
                long nr = (long)(t0 + kb + 5);
                float aB0 = Ab[(nr + 0) * U_DIM + u];
                float aB1 = Ab[(nr + 1) * U_DIM + u];
                float aB2 = Ab[(nr + 2) * U_DIM + u];
                float aB3 = Ab[(nr + 3) * U_DIM + u];
                float bB0 = Bb[(nr + 0) * U_DIM + u];
                float bB1 = Bb[(nr + 1) * U_DIM + u];
                float bB2 = Bb[(nr + 2) * U_DIM + u];
                float bB3 = Bb[(nr + 3) * U_DIM + u];
                float pB0 = valu ? Pb[(nr + 0) * U_DIM + u] : NEGINF;
                float pB1 = valu ? Pb[(nr + 1) * U_DIM + u] : NEGINF;
                float pB2 = valu ? Pb[(nr + 2) * U_DIM + u] : NEGINF;
                float pB3 = valu ? Pb[(nr + 3) * U_DIM + u] : NEGINF;
                LSTEP(t0 + kb + 0, aA0, bA0, pA0)
                LSTEP(t0 + kb + 1, aA1, bA1, pA1)
                LSTEP(t0 + kb + 2, aA2, bA2, pA2)
                LSTEP(t0 + kb + 3, aA3, bA3, pA3)
                aA0 = aB0; aA1 = aB1; aA2 = aB2; aA3 = aB3;
                bA0 = bB0; bA1 = bB1; bA2 = bB2; bA3 = bB3;
                pA0 = pB0; pA1 = pB1; pA2 = pB2; pA3 = pB3;
            }
            LSTEP(t0 + 124, aA0, bA0, pA0)
            shm[c][u] = m; shs[c][u] = ssum;
        }
    }
    __syncthreads();
    if (tid < U_DIM) {
        float M = NEGINF;
#pragma unroll
        for (int c = 0; c < 8; ++c) M = fmaxf(M, shm[c][tid]);
        float lu = NEGINF;
        if (M != NEGINF) {
            float s = 0.0f;
#pragma unroll
            for (int c = 0; c < 8; ++c) {
                float mc = shm[c][tid];
                if (mc != NEGINF) s += shs[c][tid] * __expf(mc - M);
            }
            lu = M + __logf(s);
        }
        shlu[tid] = lu;
    }
    __syncthreads();
    if (tid == 0) {
        int cnt = 0;
        for (int u = 0; u < U_DIM; ++u) cnt += (shlu[u] != NEGINF) ? 1 : 0;
        int last = cnt - 1;
        last = last < 0 ? 0 : (last > U_DIM - 1 ? U_DIM - 1 : last);
        out[b] = -shlu[last];
    }
}

// =================== fallback (small ws): round-1-style direct path =========
extern "C" __global__ void __launch_bounds__(256)
brctc_fwd_fb(const float* __restrict__ nnet, const int* __restrict__ ys,
             const int* __restrict__ hlens, const int* __restrict__ ylens,
             float* __restrict__ a_l)
{
    const int b = blockIdx.x;
    const int s = threadIdx.x;
    __shared__ float sh_a[201];
    __shared__ int   sh_ys[U_DIM];
    if (s < U_DIM) sh_ys[s] = ys[b * U_DIM + s];
    __syncthreads();
    const int hl = hlens[b], yl = ylens[b];
    int lab = 0; bool skip = false;
    if (s < 201) {
        if (s & 1) lab = sh_ys[(s - 1) >> 1];
        if ((s & 1) && s >= 3) skip = (sh_ys[(s - 1) >> 1] != sh_ys[(s - 3) >> 1]);
        sh_a[s] = (s == 0) ? 0.0f : NEGINF;
    }
    const bool valid = (s < 201) && (s <= 2 * yl);
    const bool isodd = (s < 201) && (s & 1);
    const int l = (s - 1) >> 1;
    const float* base = nnet + (size_t)b * T_DIM * C_DIM;
    float* alb = a_l + (size_t)b * T_DIM * U_DIM;
    __syncthreads();
    float p_cur = valid ? base[lab] : NEGINF;
    for (int t = 0; t < T_DIM; ++t) {
        float p_nxt = (valid && (t + 1 < T_DIM)) ? base[(size_t)(t + 1) * C_DIM + lab] : NEGINF;
        float x1 = (s < 201) ? sh_a[s] : NEGINF;
        float x2 = (s >= 1 && s < 201) ? sh_a[s - 1] : NEGINF;
        float x3 = skip ? sh_a[s - 2] : NEGINF;
        float anew = p_cur + lse3f(x1, x2, x3);
        __syncthreads();
        if (s < 201) sh_a[s] = anew;
        if (isodd) alb[t * U_DIM + l] = (t < hl) ? anew : NEGINF;
        __syncthreads();
        p_cur = p_nxt;
    }
}

extern "C" __global__ void __launch_bounds__(256)
brctc_bwd_fb(const float* __restrict__ nnet, const int* __restrict__ ys,
             const int* __restrict__ hlens, const int* __restrict__ ylens,
             const float* __restrict__ a_l, float* __restrict__ out)
{
    const int b = blockIdx.x;
    const int s = threadIdx.x;
    __shared__ float sh_b[201], sh_q[201], sh_lu[U_DIM];
    __shared__ int sh_ys[U_DIM];
    if (s < U_DIM) sh_ys[s] = ys[b * U_DIM + s];
    __syncthreads();
    const int hl = hlens[b], yl = ylens[b];
    int lab = 0; bool skip2 = false;
    if (s < 201) {
        if (s & 1) lab = sh_ys[(s - 1) >> 1];
        int s2 = s + 2;
        if (s2 < 201 && (s2 & 1) && s2 >= 3)
            skip2 = (sh_ys[(s2 - 1) >> 1] != sh_ys[(s2 - 3) >> 1]);
        sh_b[s] = NEGINF;
    }
    const bool valid = (s < 201) && (s <= 2 * yl);
    const bool isodd = (s < 201) && (s & 1);
    const int l = (s - 1) >> 1;
    const float fin0 = (s == 2 * yl || s == 2 * yl - 1) ? 0.0f : NEGINF;
    const float* base = nnet + (size_t)b * T_DIM * C_DIM;
    const float* alb = a_l + (size_t)b * T_DIM * U_DIM;
    float m_run = NEGINF, acc = 0.0f, prev_bl = NEGINF, p_hi = NEGINF;
    __syncthreads();
    for (int t = T_DIM - 1; t >= 0; --t) {
        float p_lo = valid ? base[(size_t)t * C_DIM + lab] : NEGINF;
        float a_cur = isodd ? alb[t * U_DIM + l] : NEGINF;
        float q = (s < 201) ? (p_hi + sh_b[s]) : NEGINF;
        if (s < 201) sh_q[s] = q;
        __syncthreads();
        float q2 = (s + 1 < 201) ? sh_q[s + 1] : NEGINF;
        float q3 = skip2 ? sh_q[s + 2] : NEGINF;
        float cand = lse3f(q, q2, q3);
        float bnew = (t == hl - 1) ? fin0 : cand;
        if (s < 201) sh_b[s] = bnew;
        if (isodd) {
            float bl_t = (a_cur == NEGINF) ? NEGINF : bnew;
            float bp = (t == T_DIM - 1) ? bl_t : log_sub_expf(bl_t, prev_bl + p_hi);
            float x = a_cur + bp - 0.1f * ((float)t / (float)hl);
            if (x != NEGINF) {
                if (x <= m_run) acc += __expf(x - m_run);
                else { acc = acc * __expf(m_run - x) + 1.0f; m_run = x; }
            }
            prev_bl = bl_t;
        }
        __syncthreads();
        p_hi = p_lo;
    }
    if (isodd) sh_lu[l] = (m_run == NEGINF) ? NEGINF : (m_run + __logf(acc));
    __syncthreads();
    if (s == 0) {
        int cnt = 0;
        for (int u = 0; u < U_DIM; ++u) cnt += (sh_lu[u] != NEGINF) ? 1 : 0;
        int last = cnt - 1;
        last = last < 0 ? 0 : (last > U_DIM - 1 ? U_DIM - 1 : last);
        out[b] = -sh_lu[last];
    }
}

extern "C" void kernel_launch(void* const* d_in, const int* in_sizes, int n_in,
                              void* d_out, int out_size, void* d_ws, size_t ws_size,
                              hipStream_t stream) {
    const float* nnet  = (const float*)d_in[0];
    const int*   ys    = (const int*)d_in[1];
    const int*   hlens = (const int*)d_in[2];
    const int*   ylens = (const int*)d_in[3];
    float*       outp  = (float*)d_out;
    const int B = in_sizes[2];
    const size_t TP = T_DIM + 2 * PAD;
    const size_t szP  = (size_t)B * TP * U_DIM;
    const size_t szA  = (size_t)B * AROWS * U_DIM;
    const size_t need = (szP + 2 * szA) * sizeof(float);

    if (ws_size >= need) {
        float* P    = (float*)d_ws;
        float* A    = P + szP;
        float* Braw = A + szA;
        brctc_fused<<<B, 1024, 0, stream>>>(nnet, ys, hlens, ylens, P, A, Braw, outp);
    } else {
        float* A = (float*)d_ws;
        brctc_fwd_fb<<<B, 256, 0, stream>>>(nnet, ys, hlens, ylens, A);
        brctc_bwd_fb<<<B, 256, 0, stream>>>(nnet, ys, hlens, ylens, A, outp);
    }
}

// Round 6
// 345.530 us; speedup vs baseline: 1.6132x; 1.0660x over previous
//
#include <hip/hip_runtime.h>
#include <math.h>

#define T_DIM 1000
#define C_DIM 500
#define U_DIM 100
#define PAD   16          // head/tail padding rows for P
#define AROWS (T_DIM + 5) // A/Braw rows (loss pipeline reads to row T+4)
#define NEGINF (-INFINITY)
#define LROW  120         // LDS row stride in floats; cols 100..119 = -inf pad

// ---- scalar lse helpers: bit-identical to reference op order (validated
// rounds r1-r5, absmax 0.0).  All-dead case -> NaN -> fmaxf(r,-inf) = -inf.
__device__ __forceinline__ float lse2s(float a, float b) {
    float m = fmaxf(a, b), mn = fminf(a, b);
    float r = m + __logf(1.0f + __expf(mn - m));
    return fmaxf(r, NEGINF);
}
__device__ __forceinline__ float lse3s(float x1, float x2, float x3) {
    float m = fmaxf(fmaxf(x1, x2), x3);
    float r = m + __logf(__expf(x1 - m) + __expf(x2 - m) + __expf(x3 - m));
    return fmaxf(r, NEGINF);
}
// scalar lse3 for the fallback kernels (original guard form)
__device__ __forceinline__ float lse3f(float x1, float x2, float x3) {
    float m = fmaxf(fmaxf(x1, x2), x3);
    if (m == NEGINF) return NEGINF;
    return m + __logf(__expf(x1 - m) + __expf(x2 - m) + __expf(x3 - m));
}

// Bug-compatible replica of reference _log_sub_exp (incl. inf-substitution quirk).
__device__ __forceinline__ float log_sub_expf(float a, float b) {
    bool ia = isinf(a), ib = isinf(b);
    if (!ia && !ib) {
        float ans = b + __logf(__expf(a - b) - 1.0f);
        if (isinf(ans)) ans = -2001.0f + __logf(__expf(1.0f) - 1.0f);
        return ans;
    }
    if (!ia && ib) return a;
    return NEGINF;
}

// DPP lane shifts (validated bit-exact rounds 6-10)
__device__ __forceinline__ float dpp_shr1(float x) {  // lane L <- L-1; lane0 <- -inf
    int r = __builtin_amdgcn_update_dpp(__float_as_int(NEGINF), __float_as_int(x),
                                        0x138, 0xF, 0xF, false);  // wave_shr:1
    return __int_as_float(r);
}
__device__ __forceinline__ float dpp_shl1(float x) {  // lane L <- L+1; lane63 <- -inf
    int r = __builtin_amdgcn_update_dpp(__float_as_int(NEGINF), __float_as_int(x),
                                        0x130, 0xF, 0xF, false);  // wave_shl:1
    return __int_as_float(r);
}

// ---- loss step (verbatim r10) ----------------------------------------------
#define LSTEP(tt, RA, RB, RP)                                                \
    {                                                                        \
        float a_nx = (RA), br_nx = (RB), p_nx = (RP);                        \
        float bl   = (a_t  == NEGINF) ? NEGINF : braw_t;                     \
        float term = (a_nx == NEGINF) ? NEGINF : (br_nx + p_nx);             \
        float bp = log_sub_expf(bl, term);                                   \
        float x = a_t + bp - 0.1f * (float)(tt) * inv_hl;                    \
        if (x != NEGINF) {                                                   \
            float nm = fmaxf(m, x);                                          \
            ssum = ssum * __expf(m - nm) + __expf(x - nm);                   \
            m = nm;                                                          \
        }                                                                    \
        a_t = a_nx; braw_t = br_nx;                                          \
    }

// ---- loader gather: 50 rows x (100 labels + blank) straight from nnet ------
__device__ __forceinline__ void gather_chunk(
    const float* __restrict__ nb, const int* __restrict__ shY, int yl,
    float* __restrict__ lds, float* __restrict__ ldsb,
    float* __restrict__ Pg /* global row0 base, or nullptr */,
    int row0, int j)
{
#pragma unroll
    for (int k = 0; k < 17; ++k) {
        int i = j + k * 384;                 // 384 loader threads per direction
        if (i < 6400) {                      // 50 rows x 128 slots
            int r = i >> 7, q = i & 127;
            if (q <= 100) {
                int row = row0 + r;
                int col = (q < 100) ? shY[q] : 0;
                float v = (row < T_DIM) ? nb[(size_t)row * C_DIM + col] : NEGINF;
                if (q < 100) {
                    lds[r * LROW + q] = (q < yl) ? v : NEGINF;
                    if (Pg) Pg[(size_t)r * U_DIM + q] = v;
                } else {
                    ldsb[r] = v;
                }
            }
        }
    }
}

// ======================= scan step macros (2 states/lane) ===================
// Arithmetic verbatim r4/r5 (HW-validated bit-exact, absmax 0.0).  Sync model:
// consumer waves lag a FULL CHUNK behind producers; the per-iteration
// __syncthreads provides all relay visibility (no polls, no counters).
// Rings are 128 slots: max producer/consumer index gap = 100 < 128.

// FWD producer (states 0..100; lane L: E=s2L, O=s2L+1; lane50 O dead):
#define FWP(j, pOv, gv)                                                      \
    {                                                                        \
        float Osh = dpp_shr1(O0);                                            \
        float nE = (mzE_lo + (gv)) + lse2s(E0, Osh);                         \
        float nO = (pOv) + lse3s(O0, E0, Osh + mskFlo);                      \
        float nOsh = dpp_shr1(nO);                                           \
        if (L == 50)                                                         \
            ((float2*)rlyF)[(tbk + (j)) & 127] = make_float2(nOsh, nE);      \
        E0 = nE; O0 = nO;                                                    \
        if (st) stA[(j) * U_DIM] = nO;                                       \
    }

// FWD consumer (states 101..200; lane L: O=s101+2L, E=s102+2L):
#define FWC(j, pOv, gv, rv)                                                  \
    {                                                                        \
        float Esh = dpp_shr1(E0); Esh = (L == 0) ? (rv).y : Esh;             \
        float Osh = dpp_shr1(O0); Osh = (L == 0) ? (rv).x : Osh;             \
        float nE = (mzE_hi + (gv)) + lse2s(E0, O0);                          \
        float nO = (pOv) + lse3s(O0, Esh, Osh + mskFhi);                     \
        E0 = nE; O0 = nO;                                                    \
        if (st) stA[(j) * U_DIM] = nO;                                       \
    }

// BWD producer (states 101..200): relay q[101] (lane0 qO) each step.
#define BWP(j, pOv, gv, FINF)                                                \
    {                                                                        \
        const int t_ = tbk - (j);                                            \
        float qE = (mzE_hi + (gv)) + BE;                                     \
        float qO = (pOv) + BO;                                               \
        if (L == 0) rlyB[(999 - t_) & 127] = qO;                             \
        float qOsh = dpp_shl1(qO);                                           \
        float nE = lse2s(qE, qOsh);                                          \
        float nO = lse3s(qO, qE, qOsh + mskBhi);                             \
        if (FINF) { const bool fin = (t_ == hl1);                            \
            BE = fin ? fE_hi : nE; BO = fin ? fO_hi : nO;                    \
        } else { BE = nE; BO = nO; }                                         \
        if (st) stB[-(int)((j) * U_DIM)] = BO;                               \
    }

// BWD consumer (states 0..100): inject relayed q[101] at lane50's qO.
#define BWC(j, pOv, gv, FINF, rq)                                            \
    {                                                                        \
        const int t_ = tbk - (j);                                            \
        float qE = (mzE_lo + (gv)) + BE;                                     \
        float qO = (pOv) + BO;                                               \
        qO = (L == 50) ? (rq) : qO;                                          \
        float qEsh = dpp_shl1(qE);                                           \
        float qOsh = dpp_shl1(qO);                                           \
        float nE = lse2s(qE, qO);                                            \
        float nO = lse3s(qO, qEsh, qOsh + mskBlo);                           \
        if (FINF) { const bool fin = (t_ == hl1);                            \
            BE = fin ? fE_lo : nE; BO = fin ? fO_lo : nO;                    \
        } else { BE = nE; BO = nO; }                                         \
        if (st) stB[-(int)((j) * U_DIM)] = BO;                               \
    }

#define BWP_BLOCK(FINF)                                                      \
    {                                                                        \
        const int tbk = tb2 + kk;                                            \
        float p0 = bb2[(kk-0)*LROW + 50 + L], p1 = bb2[(kk-1)*LROW + 50 + L],\
              p2 = bb2[(kk-2)*LROW + 50 + L], p3 = bb2[(kk-3)*LROW + 50 + L],\
              p4 = bb2[(kk-4)*LROW + 50 + L], p5 = bb2[(kk-5)*LROW + 50 + L],\
              p6 = bb2[(kk-6)*LROW + 50 + L], p7 = bb2[(kk-7)*LROW + 50 + L],\
              p8 = bb2[(kk-8)*LROW + 50 + L], p9 = bb2[(kk-9)*LROW + 50 + L];\
        float g0 = bp2[kk-0], g1 = bp2[kk-1], g2 = bp2[kk-2], g3 = bp2[kk-3],\
              g4 = bp2[kk-4], g5 = bp2[kk-5], g6 = bp2[kk-6], g7 = bp2[kk-7],\
              g8 = bp2[kk-8], g9 = bp2[kk-9];                                \
        BWP(0,p0,g0,FINF) BWP(1,p1,g1,FINF) BWP(2,p2,g2,FINF)                \
        BWP(3,p3,g3,FINF) BWP(4,p4,g4,FINF) BWP(5,p5,g5,FINF)                \
        BWP(6,p6,g6,FINF) BWP(7,p7,g7,FINF) BWP(8,p8,g8,FINF)                \
        BWP(9,p9,g9,FINF)                                                    \
        stB -= 10 * U_DIM;                                                   \
    }

#define BWC_BLOCK(FINF)                                                      \
    {                                                                        \
        const int tbk = tb2 + kk;                                            \
        const int kb = 999 - tbk;                                            \
        float q0 = rlyB[(kb+0)&127], q1 = rlyB[(kb+1)&127],                  \
              q2 = rlyB[(kb+2)&127], q3 = rlyB[(kb+3)&127],                  \
              q4 = rlyB[(kb+4)&127], q5 = rlyB[(kb+5)&127],                  \
              q6 = rlyB[(kb+6)&127], q7 = rlyB[(kb+7)&127],                  \
              q8 = rlyB[(kb+8)&127], q9 = rlyB[(kb+9)&127];                  \
        float p0 = bb2[(kk-0)*LROW + L], p1 = bb2[(kk-1)*LROW + L],          \
              p2 = bb2[(kk-2)*LROW + L], p3 = bb2[(kk-3)*LROW + L],          \
              p4 = bb2[(kk-4)*LROW + L], p5 = bb2[(kk-5)*LROW + L],          \
              p6 = bb2[(kk-6)*LROW + L], p7 = bb2[(kk-7)*LROW + L],          \
              p8 = bb2[(kk-8)*LROW + L], p9 = bb2[(kk-9)*LROW + L];          \
        float g0 = bp2[kk-0], g1 = bp2[kk-1], g2 = bp2[kk-2], g3 = bp2[kk-3],\
              g4 = bp2[kk-4], g5 = bp2[kk-5], g6 = bp2[kk-6], g7 = bp2[kk-7],\
              g8 = bp2[kk-8], g9 = bp2[kk-9];                                \
        BWC(0,p0,g0,FINF,q0) BWC(1,p1,g1,FINF,q1) BWC(2,p2,g2,FINF,q2)       \
        BWC(3,p3,g3,FINF,q3) BWC(4,p4,g4,FINF,q4) BWC(5,p5,g5,FINF,q5)       \
        BWC(6,p6,g6,FINF,q6) BWC(7,p7,g7,FINF,q7) BWC(8,p8,g8,FINF,q8)       \
        BWC(9,p9,g9,FINF,q9)                                                 \
        stB -= 10 * U_DIM;                                                   \
    }

// ---- fused: 4 scan waves (chunk-skewed pipeline) + 12 loader waves ---------
extern "C" __global__ void __launch_bounds__(1024)
brctc_fused(const float* __restrict__ nnet, const int* __restrict__ ys,
            const int* __restrict__ hlens, const int* __restrict__ ylens,
            float* __restrict__ P,
            float* __restrict__ A, float* __restrict__ Braw,
            float* __restrict__ out)
{
    const int b = blockIdx.x;
    const int tid = threadIdx.x;
    const int w = tid >> 6, L = tid & 63;
    const int hl = hlens[b], yl = ylens[b];
    const int hl1 = hl - 1;
    const size_t TP = T_DIM + 2 * PAD;
    const float* nb = nnet + (size_t)b * T_DIM * C_DIM;
    float* Pw = P + ((size_t)b * TP + PAD) * U_DIM;   // rows 0..T (+tail pad)
    const float* Pb = Pw;                             // loss-phase reads
    const int* ysb = ys + b * U_DIM;
    float* Ab = A    + (size_t)b * AROWS * U_DIM;
    float* Bb = Braw + (size_t)b * AROWS * U_DIM;

    // 3 chunk buffers per direction: producer i%3, consumer (i-1)%3,
    // loaders (i+1)%3 — all distinct mod 3.
    __shared__ __align__(16) float fbuf[3][50 * LROW];
    __shared__ __align__(16) float bbuf[3][50 * LROW];
    __shared__ float fpb[3][56], bpb[3][56];
    __shared__ float shm[8][U_DIM], shs[8][U_DIM], shlu[U_DIM];
    __shared__ int shY[U_DIM];
    __shared__ __align__(8) float rlyF[256];  // 128 slots x (a99,a100)
    __shared__ float rlyB[128];               // 128 slots x q101

    if (tid < U_DIM) shY[tid] = ysb[tid];

    // ---- per-lane scan constants (all threads compute; waves 0-3 use) ----
    const int cl = U_DIM - 1;
    const int yL   = ysb[min(L, cl)];
    const int yLm1 = ysb[min(max(L - 1, 0), cl)];
    const int yLp1 = ysb[min(L + 1, cl)];
    const int y50L = ysb[min(50 + L, cl)];
    const int y49L = ysb[min(49 + L, cl)];
    const int y51L = ysb[min(51 + L, cl)];
    const int ty = 2 * yl;
    const bool st = (L < 50);
    const float mzE_lo = (L <= 50 && 2 * L <= ty)       ? 0.0f : NEGINF;
    const float mzE_hi = (L <= 49 && 102 + 2 * L <= ty) ? 0.0f : NEGINF;
    const float mskFlo = (L >= 1 && yL != yLm1)  ? 0.0f : NEGINF;
    const float mskFhi = (y50L != y49L)          ? 0.0f : NEGINF;
    const float mskBhi = (L <= 48 && y51L != y50L) ? 0.0f : NEGINF;
    const float mskBlo = (yLp1 != yL)            ? 0.0f : NEGINF;
    const float fE_lo = (2*L     == ty || 2*L     == ty-1) ? 0.0f : NEGINF;
    const float fO_lo = (2*L+1   == ty || 2*L+1   == ty-1) ? 0.0f : NEGINF;
    const float fE_hi = (102+2*L == ty || 102+2*L == ty-1) ? 0.0f : NEGINF;
    const float fO_hi = (101+2*L == ty || 101+2*L == ty-1) ? 0.0f : NEGINF;

    float E0, O0, BE, BO;
    E0 = (w == 0 && L == 0) ? 0.0f : NEGINF;   // fwd-lo a[0]=0
    O0 = NEGINF; BE = NEGINF; BO = NEGINF;

    __syncthreads();   // shY ready for loaders

    // ---- prologue: ring init + pads + gather fwd chunk 0 / bwd chunk 19 ---
    if (w == 0 && L == 0)
        ((float2*)rlyF)[127] = make_float2(NEGINF, NEGINF);  // a_{-1}[99,100]
    if (w >= 4) {
        int j2 = tid - 256;                 // 0..767: -inf pads for all 6 bufs
        for (int i = j2; i < 6 * 50 * 20; i += 768) {
            int buf = i / 1000, rem = i % 1000;
            int r = rem / 20, q = 100 + rem % 20;
            float* base = (buf == 0) ? fbuf[0] : (buf == 1) ? fbuf[1]
                        : (buf == 2) ? fbuf[2] : (buf == 3) ? bbuf[0]
                        : (buf == 4) ? bbuf[1] : bbuf[2];
            base[r * LROW + q] = NEGINF;
        }
    }
    if (w >= 4 && w < 10) {                // fwd loaders (waves 4..9, 384 thr)
        int j = tid - 256;
        gather_chunk(nb, shY, yl, fbuf[0], fpb[0], Pw, 0, j);
        if (j < U_DIM) Pw[(size_t)T_DIM * U_DIM + j] = NEGINF;  // P row 1000
    } else if (w >= 10) {                  // bwd loaders (waves 10..15)
        int j = tid - 640;
        gather_chunk(nb, shY, yl, bbuf[0], bpb[0], nullptr, 951, j);
    }
    __syncthreads();

    // ---- 21 iterations: producers chunk i, consumers chunk i-1 ------------
    for (int i = 0; i < 21; ++i) {
        if (w == 0) {                       // FWD producer: states 0..100
            if (i < 20) {
                const float* fb = fbuf[i % 3];
                const float* fp = fpb[i % 3];
                const int tb = 50 * i;
                float* stA = Ab + (size_t)tb * U_DIM + L;
                for (int kk = 0; kk < 50; kk += 10) {
                    const int tbk = tb + kk;
                    float p0 = fb[(kk+0)*LROW + L], p1 = fb[(kk+1)*LROW + L],
                          p2 = fb[(kk+2)*LROW + L], p3 = fb[(kk+3)*LROW + L],
                          p4 = fb[(kk+4)*LROW + L], p5 = fb[(kk+5)*LROW + L],
                          p6 = fb[(kk+6)*LROW + L], p7 = fb[(kk+7)*LROW + L],
                          p8 = fb[(kk+8)*LROW + L], p9 = fb[(kk+9)*LROW + L];
                    float g0 = fp[kk+0], g1 = fp[kk+1], g2 = fp[kk+2],
                          g3 = fp[kk+3], g4 = fp[kk+4], g5 = fp[kk+5],
                          g6 = fp[kk+6], g7 = fp[kk+7], g8 = fp[kk+8],
                          g9 = fp[kk+9];
                    FWP(0,p0,g0) FWP(1,p1,g1) FWP(2,p2,g2) FWP(3,p3,g3)
                    FWP(4,p4,g4) FWP(5,p5,g5) FWP(6,p6,g6) FWP(7,p7,g7)
                    FWP(8,p8,g8) FWP(9,p9,g9)
                    stA += 10 * U_DIM;
                }
            }
        } else if (w == 1) {                // FWD consumer: states 101..200
            if (i >= 1) {
                const int ci = i - 1;
                const float* fb = fbuf[ci % 3];
                const float* fp = fpb[ci % 3];
                const int tb = 50 * ci;
                float* stA = Ab + (size_t)tb * U_DIM + 50 + L;
                for (int kk = 0; kk < 50; kk += 10) {
                    const int tbk = tb + kk;
                    const float2* rf = (const float2*)rlyF;
                    float2 v0 = rf[(tbk + 127) & 127], v1 = rf[(tbk + 0) & 127],
                           v2 = rf[(tbk + 1) & 127],   v3 = rf[(tbk + 2) & 127],
                           v4 = rf[(tbk + 3) & 127],   v5 = rf[(tbk + 4) & 127],
                           v6 = rf[(tbk + 5) & 127],   v7 = rf[(tbk + 6) & 127],
                           v8 = rf[(tbk + 7) & 127],   v9 = rf[(tbk + 8) & 127];
                    float p0 = fb[(kk+0)*LROW + 50 + L], p1 = fb[(kk+1)*LROW + 50 + L],
                          p2 = fb[(kk+2)*LROW + 50 + L], p3 = fb[(kk+3)*LROW + 50 + L],
                          p4 = fb[(kk+4)*LROW + 50 + L], p5 = fb[(kk+5)*LROW + 50 + L],
                          p6 = fb[(kk+6)*LROW + 50 + L], p7 = fb[(kk+7)*LROW + 50 + L],
                          p8 = fb[(kk+8)*LROW + 50 + L], p9 = fb[(kk+9)*LROW + 50 + L];
                    float g0 = fp[kk+0], g1 = fp[kk+1], g2 = fp[kk+2],
                          g3 = fp[kk+3], g4 = fp[kk+4], g5 = fp[kk+5],
                          g6 = fp[kk+6], g7 = fp[kk+7], g8 = fp[kk+8],
                          g9 = fp[kk+9];
                    FWC(0,p0,g0,v0) FWC(1,p1,g1,v1) FWC(2,p2,g2,v2) FWC(3,p3,g3,v3)
                    FWC(4,p4,g4,v4) FWC(5,p5,g5,v5) FWC(6,p6,g6,v6) FWC(7,p7,g7,v7)
                    FWC(8,p8,g8,v8) FWC(9,p9,g9,v9)
                    stA += 10 * U_DIM;
                }
            }
        } else if (w == 2) {                // BWD producer: states 101..200
            if (i < 20) {
                const float* bb2 = bbuf[i % 3];
                const float* bp2 = bpb[i % 3];
                const int cc = 19 - i;
                const int tb2 = 50 * cc;
                float* stB = Bb + (size_t)(tb2 + 49) * U_DIM + 50 + L;
                if (hl1 >= tb2 && hl1 <= tb2 + 49) {
                    for (int kk = 49; kk >= 9; kk -= 10) BWP_BLOCK(true)
                } else {
                    for (int kk = 49; kk >= 9; kk -= 10) BWP_BLOCK(false)
                }
            }
        } else if (w == 3) {                // BWD consumer: states 0..100
            if (i >= 1) {
                const int ci = i - 1;
                const float* bb2 = bbuf[ci % 3];
                const float* bp2 = bpb[ci % 3];
                const int cc = 19 - ci;
                const int tb2 = 50 * cc;
                float* stB = Bb + (size_t)(tb2 + 49) * U_DIM + L;
                if (hl1 >= tb2 && hl1 <= tb2 + 49) {
                    for (int kk = 49; kk >= 9; kk -= 10) BWC_BLOCK(true)
                } else {
                    for (int kk = 49; kk >= 9; kk -= 10) BWC_BLOCK(false)
                }
            }
        } else if (i < 19) {                // loaders: gather chunk i+1
            const int bi = (i + 1) % 3;
            if (w < 10) {
                int j = tid - 256;
                int row0 = (i + 1) * 50;                       // rows 50..950
                gather_chunk(nb, shY, yl, fbuf[bi], fpb[bi],
                             Pw + (size_t)row0 * U_DIM, row0, j);
            } else {
                int j = tid - 640;
                int row0 = (18 - i) * 50 + 1;                  // rows 1..901
                gather_chunk(nb, shY, yl, bbuf[bi], bpb[bi],
                             nullptr, row0, j);
            }
        }
        __syncthreads();
    }

    // sentinel row T = -inf (a_next at t = T-1 in loss phase)
    if (w == 0 && st)
        ((float2*)(Ab + (size_t)T_DIM * U_DIM))[L] = make_float2(NEGINF, NEGINF);

    // ---- post-fill: alpha rows >= hl are NEGINF ---------------------------
    {
        const int r0f = min(hl, T_DIM);
        const int nrow = T_DIM + 1 - r0f;
        const int tot = nrow * 50;
        for (int i = tid; i < tot; i += 1024) {
            const int rr = r0f + i / 50, cc2 = i % 50;
            ((float2*)(Ab + (size_t)rr * U_DIM))[cc2] = make_float2(NEGINF, NEGINF);
        }
    }
    __syncthreads();

    // ---- loss phase (verbatim r10 structure) ------------------------------
    {
        const int u = tid & 127;
        const int c = tid >> 7;               // 0..7
        if (u < U_DIM) {
            const bool valu = (u < yl);
            const float inv_hl = 1.0f / (float)hl;
            const int t0 = 125 * c;
            float a_t    = Ab[(size_t)t0 * U_DIM + u];
            float braw_t = Bb[(size_t)t0 * U_DIM + u];
            float aA0 = Ab[(long)(t0 + 1) * U_DIM + u];
            float aA1 = Ab[(long)(t0 + 2) * U_DIM + u];
            float aA2 = Ab[(long)(t0 + 3) * U_DIM + u];
            float aA3 = Ab[(long)(t0 + 4) * U_DIM + u];
            float bA0 = Bb[(long)(t0 + 1) * U_DIM + u];
            float bA1 = Bb[(long)(t0 + 2) * U_DIM + u];
            float bA2 = Bb[(long)(t0 + 3) * U_DIM + u];
            float bA3 = Bb[(long)(t0 + 4) * U_DIM + u];
            float pA0 = valu ? Pb[(long)(t0 + 1) * U_DIM + u] : NEGINF;
            float pA1 = valu ? Pb[(long)(t0 + 2) * U_DIM + u] : NEGINF;
            float pA2 = valu ? Pb[(long)(t0 + 3) * U_DIM + u] : NEGINF;
            float pA3 = valu ? Pb[(long)(t0 + 4) * U_DIM + u] : NEGINF;
            float m = NEGINF, ssum = 0.0f;
            for (int kb = 0; kb <= 120; kb += 4) {
                long nr = (long)(t0 + kb + 5);
                float aB0 = Ab[(nr + 0) * U_DIM + u];
                float aB1 = Ab[(nr + 1) * U_DIM + u];
                float aB2 = Ab[(nr + 2) * U_DIM + u];
                float aB3 = Ab[(nr + 3) * U_DIM + u];
                float bB0 = Bb[(nr + 0) * U_DIM + u];
                float bB1 = Bb[(nr + 1) * U_DIM + u];
                float bB2 = Bb[(nr + 2) * U_DIM + u];
                float bB3 = Bb[(nr + 3) * U_DIM + u];
                float pB0 = valu ? Pb[(nr + 0) * U_DIM + u] : NEGINF;
                float pB1 = valu ? Pb[(nr + 1) * U_DIM + u] : NEGINF;
                float pB2 = valu ? Pb[(nr + 2) * U_DIM + u] : NEGINF;
                float pB3 = valu ? Pb[(nr + 3) * U_DIM + u] : NEGINF;
                LSTEP(t0 + kb + 0, aA0, bA0, pA0)
                LSTEP(t0 + kb + 1, aA1, bA1, pA1)
                LSTEP(t0 + kb + 2, aA2, bA2, pA2)
                LSTEP(t0 + kb + 3, aA3, bA3, pA3)
                aA0 = aB0; aA1 = aB1; aA2 = aB2; aA3 = aB3;
                bA0 = bB0; bA1 = bB1; bA2 = bB2; bA3 = bB3;
                pA0 = pB0; pA1 = pB1; pA2 = pB2; pA3 = pB3;
            }
            LSTEP(t0 + 124, aA0, bA0, pA0)
            shm[c][u] = m; shs[c][u] = ssum;
        }
    }
    __syncthreads();
    if (tid < U_DIM) {
        float M = NEGINF;
#pragma unroll
        for (int c = 0; c < 8; ++c) M = fmaxf(M, shm[c][tid]);
        float lu = NEGINF;
        if (M != NEGINF) {
            float s = 0.0f;
#pragma unroll
            for (int c = 0; c < 8; ++c) {
                float mc = shm[c][tid];
                if (mc != NEGINF) s += shs[c][tid] * __expf(mc - M);
            }
            lu = M + __logf(s);
        }
        shlu[tid] = lu;
    }
    __syncthreads();
    if (tid == 0) {
        int cnt = 0;
        for (int u = 0; u < U_DIM; ++u) cnt += (shlu[u] != NEGINF) ? 1 : 0;
        int last = cnt - 1;
        last = last < 0 ? 0 : (last > U_DIM - 1 ? U_DIM - 1 : last);
        out[b] = -shlu[last];
    }
}

// =================== fallback (small ws): round-1-style direct path =========
extern "C" __global__ void __launch_bounds__(256)
brctc_fwd_fb(const float* __restrict__ nnet, const int* __restrict__ ys,
             const int* __restrict__ hlens, const int* __restrict__ ylens,
             float* __restrict__ a_l)
{
    const int b = blockIdx.x;
    const int s = threadIdx.x;
    __shared__ float sh_a[201];
    __shared__ int   sh_ys[U_DIM];
    if (s < U_DIM) sh_ys[s] = ys[b * U_DIM + s];
    __syncthreads();
    const int hl = hlens[b], yl = ylens[b];
    int lab = 0; bool skip = false;
    if (s < 201) {
        if (s & 1) lab = sh_ys[(s - 1) >> 1];
        if ((s & 1) && s >= 3) skip = (sh_ys[(s - 1) >> 1] != sh_ys[(s - 3) >> 1]);
        sh_a[s] = (s == 0) ? 0.0f : NEGINF;
    }
    const bool valid = (s < 201) && (s <= 2 * yl);
    const bool isodd = (s < 201) && (s & 1);
    const int l = (s - 1) >> 1;
    const float* base = nnet + (size_t)b * T_DIM * C_DIM;
    float* alb = a_l + (size_t)b * T_DIM * U_DIM;
    __syncthreads();
    float p_cur = valid ? base[lab] : NEGINF;
    for (int t = 0; t < T_DIM; ++t) {
        float p_nxt = (valid && (t + 1 < T_DIM)) ? base[(size_t)(t + 1) * C_DIM + lab] : NEGINF;
        float x1 = (s < 201) ? sh_a[s] : NEGINF;
        float x2 = (s >= 1 && s < 201) ? sh_a[s - 1] : NEGINF;
        float x3 = skip ? sh_a[s - 2] : NEGINF;
        float anew = p_cur + lse3f(x1, x2, x3);
        __syncthreads();
        if (s < 201) sh_a[s] = anew;
        if (isodd) alb[t * U_DIM + l] = (t < hl) ? anew : NEGINF;
        __syncthreads();
        p_cur = p_nxt;
    }
}

extern "C" __global__ void __launch_bounds__(256)
brctc_bwd_fb(const float* __restrict__ nnet, const int* __restrict__ ys,
             const int* __restrict__ hlens, const int* __restrict__ ylens,
             const float* __restrict__ a_l, float* __restrict__ out)
{
    const int b = blockIdx.x;
    const int s = threadIdx.x;
    __shared__ float sh_b[201], sh_q[201], sh_lu[U_DIM];
    __shared__ int sh_ys[U_DIM];
    if (s < U_DIM) sh_ys[s] = ys[b * U_DIM + s];
    __syncthreads();
    const int hl = hlens[b], yl = ylens[b];
    int lab = 0; bool skip2 = false;
    if (s < 201) {
        if (s & 1) lab = sh_ys[(s - 1) >> 1];
        int s2 = s + 2;
        if (s2 < 201 && (s2 & 1) && s2 >= 3)
            skip2 = (sh_ys[(s2 - 1) >> 1] != sh_ys[(s2 - 3) >> 1]);
        sh_b[s] = NEGINF;
    }
    const bool valid = (s < 201) && (s <= 2 * yl);
    const bool isodd = (s < 201) && (s & 1);
    const int l = (s - 1) >> 1;
    const float fin0 = (s == 2 * yl || s == 2 * yl - 1) ? 0.0f : NEGINF;
    const float* base = nnet + (size_t)b * T_DIM * C_DIM;
    const float* alb = a_l + (size_t)b * T_DIM * U_DIM;
    float m_run = NEGINF, acc = 0.0f, prev_bl = NEGINF, p_hi = NEGINF;
    __syncthreads();
    for (int t = T_DIM - 1; t >= 0; --t) {
        float p_lo = valid ? base[(size_t)t * C_DIM + lab] : NEGINF;
        float a_cur = isodd ? alb[t * U_DIM + l] : NEGINF;
        float q = (s < 201) ? (p_hi + sh_b[s]) : NEGINF;
        if (s < 201) sh_q[s] = q;
        __syncthreads();
        float q2 = (s + 1 < 201) ? sh_q[s + 1] : NEGINF;
        float q3 = skip2 ? sh_q[s + 2] : NEGINF;
        float cand = lse3f(q, q2, q3);
        float bnew = (t == hl - 1) ? fin0 : cand;
        if (s < 201) sh_b[s] = bnew;
        if (isodd) {
            float bl_t = (a_cur == NEGINF) ? NEGINF : bnew;
            float bp = (t == T_DIM - 1) ? bl_t : log_sub_expf(bl_t, prev_bl + p_hi);
            float x = a_cur + bp - 0.1f * ((float)t / (float)hl);
            if (x != NEGINF) {
                if (x <= m_run) acc += __expf(x - m_run);
                else { acc = acc * __expf(m_run - x) + 1.0f; m_run = x; }
            }
            prev_bl = bl_t;
        }
        __syncthreads();
        p_hi = p_lo;
    }
    if (isodd) sh_lu[l] = (m_run == NEGINF) ? NEGINF : (m_run + __logf(acc));
    __syncthreads();
    if (s == 0) {
        int cnt = 0;
        for (int u = 0; u < U_DIM; ++u) cnt += (sh_lu[u] != NEGINF) ? 1 : 0;
        int last = cnt - 1;
        last = last < 0 ? 0 : (last > U_DIM - 1 ? U_DIM - 1 : last);
        out[b] = -sh_lu[last];
    }
}

extern "C" void kernel_launch(void* const* d_in, const int* in_sizes, int n_in,
                              void* d_out, int out_size, void* d_ws, size_t ws_size,
                              hipStream_t stream) {
    const float* nnet  = (const float*)d_in[0];
    const int*   ys    = (const int*)d_in[1];
    const int*   hlens = (const int*)d_in[2];
    const int*   ylens = (const int*)d_in[3];
    float*       outp  = (float*)d_out;
    const int B = in_sizes[2];
    const size_t TP = T_DIM + 2 * PAD;
    const size_t szP  = (size_t)B * TP * U_DIM;
    const size_t szA  = (size_t)B * AROWS * U_DIM;
    const size_t need = (szP + 2 * szA) * sizeof(float);

    if (ws_size >= need) {
        float* P    = (float*)d_ws;
        float* A    = P + szP;
        float* Braw = A + szA;
        brctc_fused<<<B, 1024, 0, stream>>>(nnet, ys, hlens, ylens, P, A, Braw, outp);
    } else {
        float* A = (float*)d_ws;
        brctc_fwd_fb<<<B, 256, 0, stream>>>(nnet, ys, hlens, ylens, A);
        brctc_bwd_fb<<<B, 256, 0, stream>>>(nnet, ys, hlens, ylens, A, outp);
    }
}